// Round 1
// baseline (581.489 us; speedup 1.0000x reference)
//
#include <hip/hip_runtime.h>

#define E_DIM 1024
#define S_LEN 1024
#define H_NUM 16
#define HD_DIM 64
#define B_NUM 8
#define DFF_DIM 4096
#define NROWS 8192  // B*S

typedef unsigned short u16;
typedef short bf16v8 __attribute__((ext_vector_type(8)));
typedef float f32x4 __attribute__((ext_vector_type(4)));

__device__ __forceinline__ u16 f2b(float f) {
  union { float f; unsigned u; } x; x.f = f;
  return (u16)((x.u + 0x7fffu + ((x.u >> 16) & 1u)) >> 16);
}

__device__ __forceinline__ void gload16(const void* g, void* l) {
  __builtin_amdgcn_global_load_lds((const __attribute__((address_space(1))) void*)g,
                                   (__attribute__((address_space(3))) void*)l, 16, 0, 0);
}

// ---------------- GEMM: C[M,N] = A[M,K] (bf16) * Bt[N,K]^T (bf16) ----------------
// MODE 0: f32 out. MODE 1: bf16 out. MODE 2: bf16 out + bias + relu. MODE 3: f32 out + bias.
template<int MODE>
__global__ __launch_bounds__(256) void gemm_bt(
    const u16* __restrict__ A, const u16* __restrict__ Bt,
    void* __restrict__ Cp, const float* __restrict__ bias,
    int M, int N, int K) {
  __shared__ u16 sA[128 * 32];
  __shared__ u16 sB[128 * 32];
  const int tid = threadIdx.x;
  const int lane = tid & 63;
  const int wave = tid >> 6;
  const int bm = blockIdx.y * 128;
  const int bn = blockIdx.x * 128;
  const int wr = (wave >> 1) * 64;
  const int wc = (wave & 1) * 64;
  const int l15 = lane & 15, l4 = lane >> 4;

  f32x4 acc[4][4];
#pragma unroll
  for (int m = 0; m < 4; m++)
#pragma unroll
    for (int n = 0; n < 4; n++) acc[m][n] = (f32x4){0.f, 0.f, 0.f, 0.f};

  const int srow = tid >> 2;   // 0..63
  const int schk = tid & 3;    // 16B chunk of 64B row
  const u16* Ag0 = A + (size_t)(bm + srow) * K + schk * 8;
  const u16* Bg0 = Bt + (size_t)(bn + srow) * K + schk * 8;
  u16* sAd = sA + tid * 8;
  u16* sBd = sB + tid * 8;

  for (int k0 = 0; k0 < K; k0 += 32) {
    gload16(Ag0 + k0, sAd);
    gload16(Ag0 + k0 + (size_t)64 * K, sAd + 2048);
    gload16(Bg0 + k0, sBd);
    gload16(Bg0 + k0 + (size_t)64 * K, sBd + 2048);
    __syncthreads();
    bf16v8 af[4], bfr[4];
#pragma unroll
    for (int m = 0; m < 4; m++)
      af[m] = *(const bf16v8*)(sA + (wr + m * 16 + l15) * 32 + l4 * 8);
#pragma unroll
    for (int n = 0; n < 4; n++)
      bfr[n] = *(const bf16v8*)(sB + (wc + n * 16 + l15) * 32 + l4 * 8);
#pragma unroll
    for (int m = 0; m < 4; m++)
#pragma unroll
      for (int n = 0; n < 4; n++)
        acc[m][n] = __builtin_amdgcn_mfma_f32_16x16x32_bf16(af[m], bfr[n], acc[m][n], 0, 0, 0);
    __syncthreads();
  }

#pragma unroll
  for (int m = 0; m < 4; m++) {
#pragma unroll
    for (int n = 0; n < 4; n++) {
      const int col = bn + wc + n * 16 + l15;
      const float bv = (MODE == 2 || MODE == 3) ? bias[col] : 0.f;
#pragma unroll
      for (int i = 0; i < 4; i++) {
        const int row = bm + wr + m * 16 + l4 * 4 + i;
        float vv = acc[m][n][i] + bv;
        if (MODE == 2) vv = fmaxf(vv, 0.f);
        if (MODE == 0 || MODE == 3)
          ((float*)Cp)[(size_t)row * N + col] = vv;
        else
          ((u16*)Cp)[(size_t)row * N + col] = f2b(vv);
      }
    }
  }
}

// ---------------- Flash attention: per (b,h), Q-tile 128 rows (4 waves x 32) ----------------
__global__ __launch_bounds__(256) void attn_fa(
    const u16* __restrict__ qg, const u16* __restrict__ kg, const u16* __restrict__ vg,
    u16* __restrict__ attn) {
  __shared__ u16 sK[128 * 64];        // [kv][d], 8 chunks/row, chunk swizzle c^(r&7)
  __shared__ u16 sVt[64 * 128];       // [d][kv], 16 chunks/row, chunk swizzle c^(d&15)
  __shared__ u16 sP[4][32 * 128];     // per-wave P, chunk swizzle c^(r&15)

  const int tid = threadIdx.x, lane = tid & 63, wave = tid >> 6;
  const int l15 = lane & 15, l4 = lane >> 4, l7 = lane & 7;
  const int bh = blockIdx.y;
  const int b = bh >> 4, h = bh & 15;
  const int qrow0 = blockIdx.x * 128 + wave * 32;
  const size_t base = (size_t)b * S_LEN * E_DIM + (size_t)h * HD_DIM;

  bf16v8 qf[2][2];
#pragma unroll
  for (int m = 0; m < 2; m++)
#pragma unroll
    for (int kk = 0; kk < 2; kk++)
      qf[m][kk] = *(const bf16v8*)(qg + base + (size_t)(qrow0 + m * 16 + l15) * E_DIM + kk * 32 + l4 * 8);

  f32x4 acc_o[2][4];
  float mrun[2][4], lrun[2][4];
#pragma unroll
  for (int m = 0; m < 2; m++) {
#pragma unroll
    for (int nd = 0; nd < 4; nd++) acc_o[m][nd] = (f32x4){0.f, 0.f, 0.f, 0.f};
#pragma unroll
    for (int i = 0; i < 4; i++) { mrun[m][i] = -1e30f; lrun[m][i] = 0.f; }
  }

  const int strow = tid >> 3;  // 0..31
  const int stchk = tid & 7;

  for (int kv0 = 0; kv0 < S_LEN; kv0 += 128) {
    // stage K: linear LDS dest, inverse-swizzled global source chunk
#pragma unroll
    for (int it = 0; it < 4; it++) {
      const int r = it * 32 + strow;
      const int gsrc = stchk ^ (strow & 7);
      gload16(kg + base + (size_t)(kv0 + r) * E_DIM + gsrc * 8, sK + it * 2048 + tid * 8);
    }
    // stage V transposed (reg roundtrip), swizzled writes
#pragma unroll
    for (int it = 0; it < 4; it++) {
      const int r = it * 32 + strow;
      bf16v8 tv = *(const bf16v8*)(vg + base + (size_t)(kv0 + r) * E_DIM + stchk * 8);
#pragma unroll
      for (int j = 0; j < 8; j++) {
        const int d = stchk * 8 + j;
        const int c = (r >> 3) ^ (d & 15);
        *(u16*)((char*)sVt + d * 256 + c * 16 + (r & 7) * 2) = (u16)tv[j];
      }
    }
    __syncthreads();

    // S = Q K^T
    f32x4 accs[2][8];
#pragma unroll
    for (int m = 0; m < 2; m++)
#pragma unroll
      for (int n = 0; n < 8; n++) accs[m][n] = (f32x4){0.f, 0.f, 0.f, 0.f};
#pragma unroll
    for (int n = 0; n < 8; n++) {
      const int r = n * 16 + l15;
      bf16v8 b0 = *(const bf16v8*)((const char*)sK + r * 128 + ((l4) ^ (r & 7)) * 16);
      bf16v8 b1 = *(const bf16v8*)((const char*)sK + r * 128 + ((4 + l4) ^ (r & 7)) * 16);
#pragma unroll
      for (int m = 0; m < 2; m++) {
        accs[m][n] = __builtin_amdgcn_mfma_f32_16x16x32_bf16(qf[m][0], b0, accs[m][n], 0, 0, 0);
        accs[m][n] = __builtin_amdgcn_mfma_f32_16x16x32_bf16(qf[m][1], b1, accs[m][n], 0, 0, 0);
      }
    }

    // online softmax (rows owned per lane: (m, i) at lane-group l4)
#pragma unroll
    for (int m = 0; m < 2; m++) {
#pragma unroll
      for (int i = 0; i < 4; i++) {
        float mx = -1e30f;
#pragma unroll
        for (int n = 0; n < 8; n++) mx = fmaxf(mx, accs[m][n][i] * 0.125f);
        mx = fmaxf(mx, __shfl_xor(mx, 1));
        mx = fmaxf(mx, __shfl_xor(mx, 2));
        mx = fmaxf(mx, __shfl_xor(mx, 4));
        mx = fmaxf(mx, __shfl_xor(mx, 8));
        const float mnew = fmaxf(mrun[m][i], mx);
        const float esc = __expf(mrun[m][i] - mnew);
        float rsum = 0.f;
#pragma unroll
        for (int n = 0; n < 8; n++) {
          const float p = __expf(accs[m][n][i] * 0.125f - mnew);
          accs[m][n][i] = p;
          rsum += p;
        }
        rsum += __shfl_xor(rsum, 1);
        rsum += __shfl_xor(rsum, 2);
        rsum += __shfl_xor(rsum, 4);
        rsum += __shfl_xor(rsum, 8);
        lrun[m][i] = lrun[m][i] * esc + rsum;
        mrun[m][i] = mnew;
#pragma unroll
        for (int nd = 0; nd < 4; nd++) acc_o[m][nd][i] *= esc;
      }
    }

    // P -> LDS (bf16, swizzled), per-wave
    u16* sPw = sP[wave];
#pragma unroll
    for (int m = 0; m < 2; m++)
#pragma unroll
      for (int n = 0; n < 8; n++)
#pragma unroll
        for (int i = 0; i < 4; i++) {
          const int r = m * 16 + l4 * 4 + i;
          const int col = n * 16 + l15;
          const int c = (col >> 3) ^ (r & 15);
          *(u16*)((char*)sPw + r * 256 + c * 16 + (col & 7) * 2) = f2b(accs[m][n][i]);
        }

    // O += P V
#pragma unroll
    for (int kk = 0; kk < 4; kk++) {
      bf16v8 pa[2];
#pragma unroll
      for (int m = 0; m < 2; m++) {
        const int r = m * 16 + l15;
        const int c = (kk * 4 + l4) ^ l15;
        pa[m] = *(const bf16v8*)((const char*)sPw + r * 256 + c * 16);
      }
#pragma unroll
      for (int nd = 0; nd < 4; nd++) {
        const int d = nd * 16 + l15;
        const int c = (kk * 4 + l4) ^ l15;
        bf16v8 vb = *(const bf16v8*)((const char*)sVt + d * 256 + c * 16);
#pragma unroll
        for (int m = 0; m < 2; m++)
          acc_o[m][nd] = __builtin_amdgcn_mfma_f32_16x16x32_bf16(pa[m], vb, acc_o[m][nd], 0, 0, 0);
      }
    }
    __syncthreads();
  }

#pragma unroll
  for (int m = 0; m < 2; m++)
#pragma unroll
    for (int i = 0; i < 4; i++) {
      const float inv = 1.f / lrun[m][i];
      const int s = qrow0 + m * 16 + l4 * 4 + i;
#pragma unroll
      for (int nd = 0; nd < 4; nd++) {
        const int d = nd * 16 + l15;
        attn[base + (size_t)s * E_DIM + d] = f2b(acc_o[m][nd][i] * inv);
      }
    }
}

// ---------------- LayerNorm (1 block = 1 row of 1024), ddof=1 ----------------
// MODE 0: y = 2*a  (ln1) ; MODE 1: y = a + b  (ln2)
template<int MODE>
__global__ __launch_bounds__(256) void ln_kernel(
    const float* __restrict__ a, const float* __restrict__ b2nd,
    const float* __restrict__ scale, const float* __restrict__ bias,
    float* __restrict__ outf, u16* __restrict__ outb) {
  const int row = blockIdx.x;
  const int tid = threadIdx.x;
  const size_t off = (size_t)row * 1024 + tid * 4;
  float4 v = *(const float4*)(a + off);
  if (MODE == 0) {
    v.x *= 2.f; v.y *= 2.f; v.z *= 2.f; v.w *= 2.f;
  } else {
    float4 u = *(const float4*)(b2nd + off);
    v.x += u.x; v.y += u.y; v.z += u.z; v.w += u.w;
  }
  float s = v.x + v.y + v.z + v.w;
  float q = v.x * v.x + v.y * v.y + v.z * v.z + v.w * v.w;
#pragma unroll
  for (int o = 1; o < 64; o <<= 1) { s += __shfl_xor(s, o); q += __shfl_xor(q, o); }
  __shared__ float red[8];
  const int wave = tid >> 6, lane = tid & 63;
  if (lane == 0) { red[wave] = s; red[4 + wave] = q; }
  __syncthreads();
  s = red[0] + red[1] + red[2] + red[3];
  q = red[4] + red[5] + red[6] + red[7];
  const float mean = s * (1.f / 1024.f);
  const float var = (q - 1024.f * mean * mean) * (1.f / 1023.f);
  const float rstd = rsqrtf(var + 1e-5f);
  const int c = tid * 4;
  float4 sc = *(const float4*)(scale + c);
  float4 bi = *(const float4*)(bias + c);
  float4 o;
  o.x = sc.x * (v.x - mean) * rstd + bi.x;
  o.y = sc.y * (v.y - mean) * rstd + bi.y;
  o.z = sc.z * (v.z - mean) * rstd + bi.z;
  o.w = sc.w * (v.w - mean) * rstd + bi.w;
  *(float4*)(outf + off) = o;
  if (outb != nullptr) {
    ushort4 ob;
    ob.x = f2b(o.x); ob.y = f2b(o.y); ob.z = f2b(o.z); ob.w = f2b(o.w);
    *(ushort4*)(outb + off) = ob;
  }
}

// ---------------- fp32 -> bf16 cast (4 elems/thread) ----------------
__global__ __launch_bounds__(256) void cast_bf16_k(const float* __restrict__ in,
                                                   u16* __restrict__ out, int n4) {
  const int i = blockIdx.x * blockDim.x + threadIdx.x;
  if (i >= n4) return;
  float4 v = *(const float4*)(in + (size_t)i * 4);
  ushort4 o;
  o.x = f2b(v.x); o.y = f2b(v.y); o.z = f2b(v.z); o.w = f2b(v.w);
  *(ushort4*)(out + (size_t)i * 4) = o;
}

// ---------------- 1024x1024 fp32 transpose + bf16 cast ----------------
__global__ __launch_bounds__(256) void transpose_cast_k(const float* __restrict__ in,
                                                        u16* __restrict__ out) {
  __shared__ float tile[32][33];
  const int tx = threadIdx.x & 31, ty = threadIdx.x >> 5;
  const int bx = blockIdx.x * 32, by = blockIdx.y * 32;
#pragma unroll
  for (int j = 0; j < 4; j++)
    tile[ty + j * 8][tx] = in[(size_t)(by + ty + j * 8) * 1024 + bx + tx];
  __syncthreads();
#pragma unroll
  for (int j = 0; j < 4; j++)
    out[(size_t)(bx + ty + j * 8) * 1024 + by + tx] = f2b(tile[tx][ty + j * 8]);
}

extern "C" void kernel_launch(void* const* d_in, const int* in_sizes, int n_in,
                              void* d_out, int out_size, void* d_ws, size_t ws_size,
                              hipStream_t stream) {
  const float* x    = (const float*)d_in[0];
  const float* in_w = (const float*)d_in[1];
  const float* out_w = (const float*)d_in[2];
  const float* ln1s = (const float*)d_in[3];
  const float* ln1b = (const float*)d_in[4];
  const float* ln2s = (const float*)d_in[5];
  const float* ln2b = (const float*)d_in[6];
  const float* w1   = (const float*)d_in[7];
  const float* b1   = (const float*)d_in[8];
  const float* w2   = (const float*)d_in[9];
  const float* b2   = (const float*)d_in[10];
  float* outp = (float*)d_out;

  char* ws = (char*)d_ws;
  // arena layout (bytes); lifetimes verified non-overlapping:
  u16*   xb    = (u16*)(ws + 0);            // 16.78MB  -> attn (alias) -> H (alias)
  u16*   qb    = (u16*)(ws + 16777216);     // 16.78MB  -> attn_out f32 (alias) -> H
  u16*   kbuf  = (u16*)(ws + 33554432);     // 16.78MB  -> (attn_out span) -> H
  u16*   vbuf  = (u16*)(ws + 50331648);     // 16.78MB  -> H
  u16*   attnb = xb;
  float* attno = (float*)(ws + 16777216);   // 33.55MB (over dead q,k)
  u16*   Hb    = (u16*)(ws + 0);            // 67.11MB (over dead xb/attn,q,k,v)
  float* x1f   = (float*)(ws + 67108864);   // 33.55MB
  u16*   x1b   = (u16*)(ws + 100663296);    // 16.78MB
  float* ffn   = (float*)(ws + 117440512);  // 33.55MB
  u16*   wkt   = (u16*)(ws + 150994944);    // weights: 4x2MB + 2x8.39MB = 25.17MB
  u16*   wqt   = wkt + 1048576;
  u16*   wvt   = wqt + 1048576;
  u16*   wot   = wvt + 1048576;
  u16*   w1b   = wot + 1048576;
  u16*   w2b   = w1b + 4194304;
  (void)ws_size; (void)in_sizes; (void)n_in; (void)out_size;

  // casts / transposes
  cast_bf16_k<<<8192, 256, 0, stream>>>(x, xb, 2097152);
  cast_bf16_k<<<4096, 256, 0, stream>>>(w1, w1b, 1048576);
  cast_bf16_k<<<4096, 256, 0, stream>>>(w2, w2b, 1048576);
  dim3 tg(32, 32);
  transpose_cast_k<<<tg, 256, 0, stream>>>(in_w + 0,       wkt);  // k uses in_weights[0]
  transpose_cast_k<<<tg, 256, 0, stream>>>(in_w + 1048576, wqt);  // q uses in_weights[1]
  transpose_cast_k<<<tg, 256, 0, stream>>>(in_w + 2097152, wvt);  // v uses in_weights[2]
  transpose_cast_k<<<tg, 256, 0, stream>>>(out_w,          wot);

  // QKV projections
  dim3 g1(8, 64);
  gemm_bt<1><<<g1, 256, 0, stream>>>(xb, wqt, qb,   nullptr, NROWS, 1024, 1024);
  gemm_bt<1><<<g1, 256, 0, stream>>>(xb, wkt, kbuf, nullptr, NROWS, 1024, 1024);
  gemm_bt<1><<<g1, 256, 0, stream>>>(xb, wvt, vbuf, nullptr, NROWS, 1024, 1024);

  // attention
  dim3 ga(8, 128);
  attn_fa<<<ga, 256, 0, stream>>>(qb, kbuf, vbuf, attnb);

  // output projection
  gemm_bt<0><<<g1, 256, 0, stream>>>(attnb, wot, attno, nullptr, NROWS, 1024, 1024);

  // ln1: x1 = LN(2*attn_out)
  ln_kernel<0><<<8192, 256, 0, stream>>>(attno, nullptr, ln1s, ln1b, x1f, x1b);

  // FFN
  dim3 g2(32, 64);
  gemm_bt<2><<<g2, 256, 0, stream>>>(x1b, w1b, Hb, b1, NROWS, 4096, 1024);
  gemm_bt<3><<<g1, 256, 0, stream>>>(Hb, w2b, ffn, b2, NROWS, 1024, 4096);

  // ln2: out = LN(x1 + ffn)
  ln_kernel<1><<<8192, 256, 0, stream>>>(x1f, ffn, ln2s, ln2b, outp, nullptr);
}

// Round 2
// 533.172 us; speedup vs baseline: 1.0906x; 1.0906x over previous
//
#include <hip/hip_runtime.h>

#define E_DIM 1024
#define S_LEN 1024
#define H_NUM 16
#define HD_DIM 64
#define B_NUM 8
#define DFF_DIM 4096
#define NROWS 8192  // B*S

typedef unsigned short u16;
typedef short bf16v8 __attribute__((ext_vector_type(8)));
typedef float f32x4 __attribute__((ext_vector_type(4)));

// softmax scale folded into Q projection: 1/sqrt(64) * log2(e)
#define QK_SCALE 0.18033688011112042f

__device__ __forceinline__ u16 f2b(float f) {
  union { float f; unsigned u; } x; x.f = f;
  return (u16)((x.u + 0x7fffu + ((x.u >> 16) & 1u)) >> 16);
}

__device__ __forceinline__ void gload16(const void* g, void* l) {
  __builtin_amdgcn_global_load_lds((const __attribute__((address_space(1))) void*)g,
                                   (__attribute__((address_space(3))) void*)l, 16, 0, 0);
}

// ---------------- GEMM: C[M,N] = A[M,K] (bf16) * Bt[N,K]^T (bf16) ----------------
// MODE 0: f32 out. MODE 1: bf16 out. MODE 2: bf16 out + bias + relu.
// MODE 3: f32 out + bias. MODE 4: bf16 out, scaled by QK_SCALE.
template<int MODE>
__global__ __launch_bounds__(256) void gemm_bt(
    const u16* __restrict__ A, const u16* __restrict__ Bt,
    void* __restrict__ Cp, const float* __restrict__ bias,
    int M, int N, int K) {
  __shared__ u16 sA[128 * 32];
  __shared__ u16 sB[128 * 32];
  const int tid = threadIdx.x;
  const int lane = tid & 63;
  const int wave = tid >> 6;
  const int bm = blockIdx.y * 128;
  const int bn = blockIdx.x * 128;
  const int wr = (wave >> 1) * 64;
  const int wc = (wave & 1) * 64;
  const int l15 = lane & 15, l4 = lane >> 4;

  f32x4 acc[4][4];
#pragma unroll
  for (int m = 0; m < 4; m++)
#pragma unroll
    for (int n = 0; n < 4; n++) acc[m][n] = (f32x4){0.f, 0.f, 0.f, 0.f};

  const int srow = tid >> 2;   // 0..63
  const int schk = tid & 3;    // 16B chunk of 64B row
  const u16* Ag0 = A + (size_t)(bm + srow) * K + schk * 8;
  const u16* Bg0 = Bt + (size_t)(bn + srow) * K + schk * 8;
  u16* sAd = sA + tid * 8;
  u16* sBd = sB + tid * 8;

  for (int k0 = 0; k0 < K; k0 += 32) {
    gload16(Ag0 + k0, sAd);
    gload16(Ag0 + k0 + (size_t)64 * K, sAd + 2048);
    gload16(Bg0 + k0, sBd);
    gload16(Bg0 + k0 + (size_t)64 * K, sBd + 2048);
    __syncthreads();
    bf16v8 af[4], bfr[4];
#pragma unroll
    for (int m = 0; m < 4; m++)
      af[m] = *(const bf16v8*)(sA + (wr + m * 16 + l15) * 32 + l4 * 8);
#pragma unroll
    for (int n = 0; n < 4; n++)
      bfr[n] = *(const bf16v8*)(sB + (wc + n * 16 + l15) * 32 + l4 * 8);
#pragma unroll
    for (int m = 0; m < 4; m++)
#pragma unroll
      for (int n = 0; n < 4; n++)
        acc[m][n] = __builtin_amdgcn_mfma_f32_16x16x32_bf16(af[m], bfr[n], acc[m][n], 0, 0, 0);
    __syncthreads();
  }

#pragma unroll
  for (int m = 0; m < 4; m++) {
#pragma unroll
    for (int n = 0; n < 4; n++) {
      const int col = bn + wc + n * 16 + l15;
      const float bv = (MODE == 2 || MODE == 3) ? bias[col] : 0.f;
#pragma unroll
      for (int i = 0; i < 4; i++) {
        const int row = bm + wr + m * 16 + l4 * 4 + i;
        float vv = acc[m][n][i] + bv;
        if (MODE == 2) vv = fmaxf(vv, 0.f);
        if (MODE == 4) vv *= QK_SCALE;
        if (MODE == 0 || MODE == 3)
          ((float*)Cp)[(size_t)row * N + col] = vv;
        else
          ((u16*)Cp)[(size_t)row * N + col] = f2b(vv);
      }
    }
  }
}

// ---------------- Flash attention, swapped-QK^T structure ----------------
// Per (b,h): Q-tile 128 rows (4 waves x 32 q). KV tiles of 128.
// S^T = K*Q^T so each lane owns full kv-columns of q = m*16 + (lane&15):
// softmax is in-lane + 2 shfl; P stays in registers (cvt_pk + bpermute
// redistribution into PV A-fragments). V^T staged conflict-free in LDS.
__global__ __launch_bounds__(256) void attn_fa(
    const u16* __restrict__ qg, const u16* __restrict__ kg, const u16* __restrict__ vg,
    u16* __restrict__ attn) {
  __shared__ u16 sK[128 * 64];    // [kv][chunk^(kv&7)][8d]  16KB
  __shared__ u16 sVt[128 * 64];   // [kv>>3][d][kv&7]        16KB

  const int tid = threadIdx.x, lane = tid & 63, wave = tid >> 6;
  const int l15 = lane & 15, l4 = lane >> 4;
  const int bh = blockIdx.y;
  const int b = bh >> 4, h = bh & 15;
  const int qrow0 = blockIdx.x * 128 + wave * 32;
  const size_t base = (size_t)b * (S_LEN * E_DIM) + (size_t)h * HD_DIM;
  const int esrc = (lane & 48) + l4 * 4;  // shfl base: lane with l15 = 4*l4+i

  // Q fragments: rows q = m*16+l15, d-contiguous (pre-scaled by QK_SCALE in GEMM)
  bf16v8 qf[2][2];
#pragma unroll
  for (int m = 0; m < 2; m++)
#pragma unroll
    for (int kk = 0; kk < 2; kk++)
      qf[m][kk] = *(const bf16v8*)(qg + base + (size_t)(qrow0 + m * 16 + l15) * E_DIM + kk * 32 + l4 * 8);

  f32x4 acc_o[2][4];   // O[q = m*16 + 4*l4 + i][d = nd*16 + l15]
  float mrun[2], lrun[2];
#pragma unroll
  for (int m = 0; m < 2; m++) {
    mrun[m] = -1e30f; lrun[m] = 0.f;
#pragma unroll
    for (int nd = 0; nd < 4; nd++) acc_o[m][nd] = (f32x4){0.f, 0.f, 0.f, 0.f};
  }

  const int strow = tid >> 3;  // 0..31
  const int s8 = tid & 7;

  for (int kv0 = 0; kv0 < S_LEN; kv0 += 128) {
    // ---- stage K: linear LDS dest, source chunk pre-swizzled ----
#pragma unroll
    for (int it = 0; it < 4; it++) {
      const int r = it * 32 + strow;
      const int gsrc = s8 ^ (r & 7);
      gload16(kg + base + (size_t)(kv0 + r) * E_DIM + gsrc * 8, sK + r * 64 + s8 * 8);
    }
    // ---- stage V^T: pair rows via shfl_xor(8), u32 writes, 2-way banks ----
#pragma unroll
    for (int it = 0; it < 4; it++) {
      const int r = it * 32 + strow;
      int4 w = *(const int4*)(vg + base + (size_t)(kv0 + r) * E_DIM + s8 * 8);
      int4 w2;
      w2.x = __shfl_xor(w.x, 8); w2.y = __shfl_xor(w.y, 8);
      w2.z = __shfl_xor(w.z, 8); w2.w = __shfl_xor(w.w, 8);
      const int t = r >> 1;
      const int odd = r & 1;
      const u16* own = (const u16*)&w;
      const u16* par = (const u16*)&w2;
      char* dstbase = (char*)sVt + (t >> 2) * 1024 + (t & 3) * 4;
#pragma unroll
      for (int k = 0; k < 4; k++) {
        // even rows write d-lane j=k; odd rows write j=4+k (static extracts)
        const unsigned lo = odd ? (unsigned)par[4 + k] : (unsigned)own[k];
        const unsigned hi = odd ? (unsigned)own[4 + k] : (unsigned)par[k];
        const int d = s8 * 8 + k + (odd ? 4 : 0);
        *(unsigned*)(dstbase + d * 16) = lo | (hi << 16);
      }
    }
    __syncthreads();

    // ---- S^T = K Q^T : T[m][n], col q = m*16+l15, row kv = n*16 + 4*l4 + i ----
    f32x4 T[2][8];
#pragma unroll
    for (int m = 0; m < 2; m++)
#pragma unroll
      for (int n = 0; n < 8; n++) T[m][n] = (f32x4){0.f, 0.f, 0.f, 0.f};
#pragma unroll
    for (int n = 0; n < 8; n++) {
      const int r = n * 16 + l15;
      const bf16v8 k0 = *(const bf16v8*)(sK + r * 64 + (l4 ^ (r & 7)) * 8);
      const bf16v8 k1 = *(const bf16v8*)(sK + r * 64 + ((4 + l4) ^ (r & 7)) * 8);
#pragma unroll
      for (int m = 0; m < 2; m++) {
        T[m][n] = __builtin_amdgcn_mfma_f32_16x16x32_bf16(k0, qf[m][0], T[m][n], 0, 0, 0);
        T[m][n] = __builtin_amdgcn_mfma_f32_16x16x32_bf16(k1, qf[m][1], T[m][n], 0, 0, 0);
      }
    }

    // ---- online softmax (log2 domain; scale folded into Q) ----
    unsigned W[2][8][2];
#pragma unroll
    for (int m = 0; m < 2; m++) {
      float mx = mrun[m];
#pragma unroll
      for (int n = 0; n < 8; n++)
        mx = fmaxf(mx, fmaxf(fmaxf(T[m][n][0], T[m][n][1]), fmaxf(T[m][n][2], T[m][n][3])));
      mx = fmaxf(mx, __shfl_xor(mx, 16));
      mx = fmaxf(mx, __shfl_xor(mx, 32));
      const float esc = exp2f(mrun[m] - mx);
      mrun[m] = mx;
      float rsum = 0.f;
#pragma unroll
      for (int n = 0; n < 8; n++)
#pragma unroll
        for (int i = 0; i < 4; i++) {
          const float p = exp2f(T[m][n][i] - mx);
          T[m][n][i] = p;
          rsum += p;
        }
      rsum += __shfl_xor(rsum, 16);
      rsum += __shfl_xor(rsum, 32);
      lrun[m] = lrun[m] * esc + rsum;
      // rescale O rows (esc uniform across l4 at fixed l15; fetch per-row value)
#pragma unroll
      for (int i = 0; i < 4; i++) {
        const float e = __shfl(esc, esrc + i);
#pragma unroll
        for (int nd = 0; nd < 4; nd++) acc_o[m][nd][i] *= e;
      }
      // pack P pairs (kv 2p,2p+1 are i-contiguous in C-layout)
#pragma unroll
      for (int n = 0; n < 8; n++)
#pragma unroll
        for (int p = 0; p < 2; p++) {
          unsigned wv;
          asm("v_cvt_pk_bf16_f32 %0, %1, %2" : "=v"(wv) : "v"(T[m][n][2 * p]), "v"(T[m][n][2 * p + 1]));
          W[m][n][p] = wv;
        }
    }

    // ---- O += P V : pa rebuilt in-register via bpermute ----
#pragma unroll
    for (int kk = 0; kk < 4; kk++) {
      bf16v8 pa[2];
#pragma unroll
      for (int m = 0; m < 2; m++) {
        union { unsigned u[4]; bf16v8 v; } c;
#pragma unroll
        for (int wd = 0; wd < 4; wd++) {
          const int src = l15 + 16 * ((2 * l4 + (wd >> 1)) & 3);
          const unsigned a0 = __shfl(W[m][2 * kk][wd & 1], src);
          const unsigned a1 = __shfl(W[m][2 * kk + 1][wd & 1], src);
          c.u[wd] = (l4 < 2) ? a0 : a1;
        }
        pa[m] = c.v;
      }
#pragma unroll
      for (int nd = 0; nd < 4; nd++) {
        const bf16v8 vb = *(const bf16v8*)(sVt + (kk * 4 + l4) * 512 + (nd * 16 + l15) * 8);
#pragma unroll
        for (int m = 0; m < 2; m++)
          acc_o[m][nd] = __builtin_amdgcn_mfma_f32_16x16x32_bf16(pa[m], vb, acc_o[m][nd], 0, 0, 0);
      }
    }
    __syncthreads();
  }

  // ---- epilogue: normalize rows, store ----
#pragma unroll
  for (int m = 0; m < 2; m++) {
    const float linv = 1.f / lrun[m];
#pragma unroll
    for (int i = 0; i < 4; i++) {
      const float li = __shfl(linv, esrc + i);
      const int s = qrow0 + m * 16 + l4 * 4 + i;
#pragma unroll
      for (int nd = 0; nd < 4; nd++)
        attn[base + (size_t)s * E_DIM + nd * 16 + l15] = f2b(acc_o[m][nd][i] * li);
    }
  }
}

// ---------------- LayerNorm (1 block = 1 row of 1024), ddof=1 ----------------
// MODE 0: y = 2*a  (ln1) ; MODE 1: y = a + b  (ln2)
template<int MODE>
__global__ __launch_bounds__(256) void ln_kernel(
    const float* __restrict__ a, const float* __restrict__ b2nd,
    const float* __restrict__ scale, const float* __restrict__ bias,
    float* __restrict__ outf, u16* __restrict__ outb) {
  const int row = blockIdx.x;
  const int tid = threadIdx.x;
  const size_t off = (size_t)row * 1024 + tid * 4;
  float4 v = *(const float4*)(a + off);
  if (MODE == 0) {
    v.x *= 2.f; v.y *= 2.f; v.z *= 2.f; v.w *= 2.f;
  } else {
    float4 u = *(const float4*)(b2nd + off);
    v.x += u.x; v.y += u.y; v.z += u.z; v.w += u.w;
  }
  float s = v.x + v.y + v.z + v.w;
  float q = v.x * v.x + v.y * v.y + v.z * v.z + v.w * v.w;
#pragma unroll
  for (int o = 1; o < 64; o <<= 1) { s += __shfl_xor(s, o); q += __shfl_xor(q, o); }
  __shared__ float red[8];
  const int wave = tid >> 6, lane = tid & 63;
  if (lane == 0) { red[wave] = s; red[4 + wave] = q; }
  __syncthreads();
  s = red[0] + red[1] + red[2] + red[3];
  q = red[4] + red[5] + red[6] + red[7];
  const float mean = s * (1.f / 1024.f);
  const float var = (q - 1024.f * mean * mean) * (1.f / 1023.f);
  const float rstd = rsqrtf(var + 1e-5f);
  const int c = tid * 4;
  float4 sc = *(const float4*)(scale + c);
  float4 bi = *(const float4*)(bias + c);
  float4 o;
  o.x = sc.x * (v.x - mean) * rstd + bi.x;
  o.y = sc.y * (v.y - mean) * rstd + bi.y;
  o.z = sc.z * (v.z - mean) * rstd + bi.z;
  o.w = sc.w * (v.w - mean) * rstd + bi.w;
  *(float4*)(outf + off) = o;
  if (outb != nullptr) {
    ushort4 ob;
    ob.x = f2b(o.x); ob.y = f2b(o.y); ob.z = f2b(o.z); ob.w = f2b(o.w);
    *(ushort4*)(outb + off) = ob;
  }
}

// ---------------- fp32 -> bf16 cast (4 elems/thread) ----------------
__global__ __launch_bounds__(256) void cast_bf16_k(const float* __restrict__ in,
                                                   u16* __restrict__ out, int n4) {
  const int i = blockIdx.x * blockDim.x + threadIdx.x;
  if (i >= n4) return;
  float4 v = *(const float4*)(in + (size_t)i * 4);
  ushort4 o;
  o.x = f2b(v.x); o.y = f2b(v.y); o.z = f2b(v.z); o.w = f2b(v.w);
  *(ushort4*)(out + (size_t)i * 4) = o;
}

// ---------------- 1024x1024 fp32 transpose + bf16 cast ----------------
__global__ __launch_bounds__(256) void transpose_cast_k(const float* __restrict__ in,
                                                        u16* __restrict__ out) {
  __shared__ float tile[32][33];
  const int tx = threadIdx.x & 31, ty = threadIdx.x >> 5;
  const int bx = blockIdx.x * 32, by = blockIdx.y * 32;
#pragma unroll
  for (int j = 0; j < 4; j++)
    tile[ty + j * 8][tx] = in[(size_t)(by + ty + j * 8) * 1024 + bx + tx];
  __syncthreads();
#pragma unroll
  for (int j = 0; j < 4; j++)
    out[(size_t)(bx + ty + j * 8) * 1024 + by + tx] = f2b(tile[tx][ty + j * 8]);
}

extern "C" void kernel_launch(void* const* d_in, const int* in_sizes, int n_in,
                              void* d_out, int out_size, void* d_ws, size_t ws_size,
                              hipStream_t stream) {
  const float* x    = (const float*)d_in[0];
  const float* in_w = (const float*)d_in[1];
  const float* out_w = (const float*)d_in[2];
  const float* ln1s = (const float*)d_in[3];
  const float* ln1b = (const float*)d_in[4];
  const float* ln2s = (const float*)d_in[5];
  const float* ln2b = (const float*)d_in[6];
  const float* w1   = (const float*)d_in[7];
  const float* b1   = (const float*)d_in[8];
  const float* w2   = (const float*)d_in[9];
  const float* b2   = (const float*)d_in[10];
  float* outp = (float*)d_out;

  char* ws = (char*)d_ws;
  u16*   xb    = (u16*)(ws + 0);            // 16.78MB  -> attn (alias) -> H (alias)
  u16*   qb    = (u16*)(ws + 16777216);     // 16.78MB  -> attn_out f32 (alias) -> H
  u16*   kbuf  = (u16*)(ws + 33554432);     // 16.78MB
  u16*   vbuf  = (u16*)(ws + 50331648);     // 16.78MB
  u16*   attnb = xb;
  float* attno = (float*)(ws + 16777216);   // 33.55MB (over dead q,k)
  u16*   Hb    = (u16*)(ws + 0);            // 67.11MB (over dead xb/attn,q,k,v)
  float* x1f   = (float*)(ws + 67108864);   // 33.55MB
  u16*   x1b   = (u16*)(ws + 100663296);    // 16.78MB
  float* ffn   = (float*)(ws + 117440512);  // 33.55MB
  u16*   wkt   = (u16*)(ws + 150994944);    // weights: 4x2MB + 2x8.39MB
  u16*   wqt   = wkt + 1048576;
  u16*   wvt   = wqt + 1048576;
  u16*   wot   = wvt + 1048576;
  u16*   w1b   = wot + 1048576;
  u16*   w2b   = w1b + 4194304;
  (void)ws_size; (void)in_sizes; (void)n_in; (void)out_size;

  // casts / transposes
  cast_bf16_k<<<8192, 256, 0, stream>>>(x, xb, 2097152);
  cast_bf16_k<<<4096, 256, 0, stream>>>(w1, w1b, 1048576);
  cast_bf16_k<<<4096, 256, 0, stream>>>(w2, w2b, 1048576);
  dim3 tg(32, 32);
  transpose_cast_k<<<tg, 256, 0, stream>>>(in_w + 0,       wkt);  // k uses in_weights[0]
  transpose_cast_k<<<tg, 256, 0, stream>>>(in_w + 1048576, wqt);  // q uses in_weights[1]
  transpose_cast_k<<<tg, 256, 0, stream>>>(in_w + 2097152, wvt);  // v uses in_weights[2]
  transpose_cast_k<<<tg, 256, 0, stream>>>(out_w,          wot);

  // QKV projections (Q pre-scaled by 0.125*log2e for exp2-domain softmax)
  dim3 g1(8, 64);
  gemm_bt<4><<<g1, 256, 0, stream>>>(xb, wqt, qb,   nullptr, NROWS, 1024, 1024);
  gemm_bt<1><<<g1, 256, 0, stream>>>(xb, wkt, kbuf, nullptr, NROWS, 1024, 1024);
  gemm_bt<1><<<g1, 256, 0, stream>>>(xb, wvt, vbuf, nullptr, NROWS, 1024, 1024);

  // attention
  dim3 ga(8, 128);
  attn_fa<<<ga, 256, 0, stream>>>(qb, kbuf, vbuf, attnb);

  // output projection
  gemm_bt<0><<<g1, 256, 0, stream>>>(attnb, wot, attno, nullptr, NROWS, 1024, 1024);

  // ln1: x1 = LN(2*attn_out)
  ln_kernel<0><<<8192, 256, 0, stream>>>(attno, nullptr, ln1s, ln1b, x1f, x1b);

  // FFN
  dim3 g2(32, 64);
  gemm_bt<2><<<g2, 256, 0, stream>>>(x1b, w1b, Hb, b1, NROWS, 4096, 1024);
  gemm_bt<3><<<g1, 256, 0, stream>>>(Hb, w2b, ffn, b2, NROWS, 1024, 4096);

  // ln2: out = LN(x1 + ffn)
  ln_kernel<1><<<8192, 256, 0, stream>>>(x1f, ffn, ln2s, ln2b, outp, nullptr);
}

// Round 3
// 467.178 us; speedup vs baseline: 1.2447x; 1.1413x over previous
//
#include <hip/hip_runtime.h>

#define E_DIM 1024
#define S_LEN 1024
#define H_NUM 16
#define HD_DIM 64
#define B_NUM 8
#define DFF_DIM 4096
#define NROWS 8192  // B*S

typedef unsigned short u16;
typedef short bf16v8 __attribute__((ext_vector_type(8)));
typedef float f32x4 __attribute__((ext_vector_type(4)));

// softmax scale folded into Q projection: 1/sqrt(64) * log2(e)
#define QK_SCALE 0.18033688011112042f

__device__ __forceinline__ u16 f2b(float f) {
  union { float f; unsigned u; } x; x.f = f;
  return (u16)((x.u + 0x7fffu + ((x.u >> 16) & 1u)) >> 16);
}

__device__ __forceinline__ void gload16(const void* g, void* l) {
  __builtin_amdgcn_global_load_lds((const __attribute__((address_space(1))) void*)g,
                                   (__attribute__((address_space(3))) void*)l, 16, 0, 0);
}

// ---------------- GEMM: C[M,N] = A[M,K] (bf16) * Bt[N,K]^T (bf16) ----------------
// MODE 0: f32 out. MODE 1: bf16 out. MODE 2: bf16 out + bias + relu.
// MODE 3: f32 out + bias. MODE 4: bf16 out, scaled by QK_SCALE.
template<int MODE>
__global__ __launch_bounds__(256) void gemm_bt(
    const u16* __restrict__ A, const u16* __restrict__ Bt,
    void* __restrict__ Cp, const float* __restrict__ bias,
    int M, int N, int K) {
  __shared__ u16 sA[128 * 32];
  __shared__ u16 sB[128 * 32];
  const int tid = threadIdx.x;
  const int lane = tid & 63;
  const int wave = tid >> 6;
  // XCD-aware block swizzle (nwg % 8 == 0 for all launches)
  const int nx = gridDim.x;
  const int lin = blockIdx.y * nx + blockIdx.x;
  const int chunk = (nx * gridDim.y) >> 3;
  const int swz = (lin & 7) * chunk + (lin >> 3);
  const int bm = (swz / nx) * 128;
  const int bn = (swz % nx) * 128;
  const int wr = (wave >> 1) * 64;
  const int wc = (wave & 1) * 64;
  const int l15 = lane & 15, l4 = lane >> 4;

  f32x4 acc[4][4];
#pragma unroll
  for (int m = 0; m < 4; m++)
#pragma unroll
    for (int n = 0; n < 4; n++) acc[m][n] = (f32x4){0.f, 0.f, 0.f, 0.f};

  const int srow = tid >> 2;   // 0..63
  const int schk = tid & 3;    // 16B chunk of 64B row
  const u16* Ag0 = A + (size_t)(bm + srow) * K + schk * 8;
  const u16* Bg0 = Bt + (size_t)(bn + srow) * K + schk * 8;
  u16* sAd = sA + tid * 8;
  u16* sBd = sB + tid * 8;

  for (int k0 = 0; k0 < K; k0 += 32) {
    gload16(Ag0 + k0, sAd);
    gload16(Ag0 + k0 + (size_t)64 * K, sAd + 2048);
    gload16(Bg0 + k0, sBd);
    gload16(Bg0 + k0 + (size_t)64 * K, sBd + 2048);
    __syncthreads();
    bf16v8 af[4], bfr[4];
#pragma unroll
    for (int m = 0; m < 4; m++)
      af[m] = *(const bf16v8*)(sA + (wr + m * 16 + l15) * 32 + l4 * 8);
#pragma unroll
    for (int n = 0; n < 4; n++)
      bfr[n] = *(const bf16v8*)(sB + (wc + n * 16 + l15) * 32 + l4 * 8);
#pragma unroll
    for (int m = 0; m < 4; m++)
#pragma unroll
      for (int n = 0; n < 4; n++)
        acc[m][n] = __builtin_amdgcn_mfma_f32_16x16x32_bf16(af[m], bfr[n], acc[m][n], 0, 0, 0);
    __syncthreads();
  }

#pragma unroll
  for (int m = 0; m < 4; m++) {
#pragma unroll
    for (int n = 0; n < 4; n++) {
      const int col = bn + wc + n * 16 + l15;
      const float bv = (MODE == 2 || MODE == 3) ? bias[col] : 0.f;
#pragma unroll
      for (int i = 0; i < 4; i++) {
        const int row = bm + wr + m * 16 + l4 * 4 + i;
        float vv = acc[m][n][i] + bv;
        if (MODE == 2) vv = fmaxf(vv, 0.f);
        if (MODE == 4) vv *= QK_SCALE;
        if (MODE == 0 || MODE == 3)
          ((float*)Cp)[(size_t)row * N + col] = vv;
        else
          ((u16*)Cp)[(size_t)row * N + col] = f2b(vv);
      }
    }
  }
}

// V^T staging: pair rows via shfl_xor(8), pack kv-pairs into u32 writes.
// Layout: sVt[kv>>3][d ^ ((d>>3)&7)][kv&7]; write-side d>>3 == s8 so the
// swizzle spreads the 8 s8-lanes across bank quads (conflict-free writes).
__device__ __forceinline__ void vt_write(u16* sVtBuf, const int4* vr, int strow, int s8) {
#pragma unroll
  for (int it = 0; it < 2; it++) {
    const int r = it * 32 + strow;
    int4 wv = vr[it];
    int4 w2;
    w2.x = __shfl_xor(wv.x, 8); w2.y = __shfl_xor(wv.y, 8);
    w2.z = __shfl_xor(wv.z, 8); w2.w = __shfl_xor(wv.w, 8);
    const int t = r >> 1;
    const int odd = r & 1;
    const u16* own = (const u16*)&wv;
    const u16* par = (const u16*)&w2;
    char* dstbase = (char*)sVtBuf + (t >> 2) * 1024 + (t & 3) * 4;
#pragma unroll
    for (int k = 0; k < 4; k++) {
      const unsigned lo = odd ? (unsigned)par[4 + k] : (unsigned)own[k];
      const unsigned hi = odd ? (unsigned)own[4 + k] : (unsigned)par[k];
      const int d = s8 * 8 + k + (odd ? 4 : 0);
      const int dsw = d ^ s8;  // d>>3 == s8
      *(unsigned*)(dstbase + dsw * 16) = lo | (hi << 16);
    }
  }
}

// ---------------- Flash attention, swapped-QK^T + async double-buffer ----------------
// 1D grid 1024, XCD-swizzled so each XCD owns 16 consecutive (b,h) (K/V ~4MB -> L2).
// Per block: 4 waves x 32 q-rows = 128 q. KV tiles of 64, double-buffered:
// tile t+1's K (global_load_lds) and V (global->reg) issued before tile t's compute.
__global__ __launch_bounds__(256) void attn_fa(
    const u16* __restrict__ qg, const u16* __restrict__ kg, const u16* __restrict__ vg,
    u16* __restrict__ attn) {
  __shared__ u16 sK[2][64 * 64];    // [kv][chunk^(kv&7)][8d]  8KB each
  __shared__ u16 sVt[2][64 * 64];   // [kv>>3][d^((d>>3)&7)][kv&7]  8KB each

  const int tid = threadIdx.x, lane = tid & 63, wave = tid >> 6;
  const int l15 = lane & 15, l4 = lane >> 4;
  const int w = ((blockIdx.x & 7) << 7) + (blockIdx.x >> 3);  // XCD swizzle
  const int bh = w >> 3;
  const int b = bh >> 4, h = bh & 15;
  const int qrow0 = (w & 7) * 128 + wave * 32;
  const size_t base = (size_t)b * (S_LEN * E_DIM) + (size_t)h * HD_DIM;
  const int esrc = (lane & 48) + l4 * 4;  // shfl base: lane with l15 = 4*l4+i

  // Q fragments: rows q = m*16+l15, d-contiguous (pre-scaled by QK_SCALE in GEMM)
  bf16v8 qf[2][2];
#pragma unroll
  for (int m = 0; m < 2; m++)
#pragma unroll
    for (int kk = 0; kk < 2; kk++)
      qf[m][kk] = *(const bf16v8*)(qg + base + (size_t)(qrow0 + m * 16 + l15) * E_DIM + kk * 32 + l4 * 8);

  f32x4 acc_o[2][4];   // O[q = m*16 + 4*l4 + i][d = nd*16 + l15]
  float mrun[2], lrun[2];
#pragma unroll
  for (int m = 0; m < 2; m++) {
    mrun[m] = -1e30f; lrun[m] = 0.f;
#pragma unroll
    for (int nd = 0; nd < 4; nd++) acc_o[m][nd] = (f32x4){0.f, 0.f, 0.f, 0.f};
  }

  const int strow = tid >> 3;  // 0..31
  const int s8 = tid & 7;

  // ---- prologue: stage tile 0 into buffer 0 ----
  {
#pragma unroll
    for (int it = 0; it < 2; it++) {
      const int r = it * 32 + strow;
      gload16(kg + base + (size_t)r * E_DIM + (s8 ^ (r & 7)) * 8, sK[0] + r * 64 + s8 * 8);
    }
    int4 v0[2];
#pragma unroll
    for (int it = 0; it < 2; it++)
      v0[it] = *(const int4*)(vg + base + (size_t)(it * 32 + strow) * E_DIM + s8 * 8);
    vt_write(sVt[0], v0, strow, s8);
    __syncthreads();
  }

  for (int t = 0; t < 16; t++) {
    const int cur = t & 1;
    int4 vreg[2];
    // ---- issue tile t+1 loads (hide latency under compute) ----
    if (t < 15) {
      const int kvn = (t + 1) * 64;
#pragma unroll
      for (int it = 0; it < 2; it++) {
        const int r = it * 32 + strow;
        gload16(kg + base + (size_t)(kvn + r) * E_DIM + (s8 ^ (r & 7)) * 8,
                sK[cur ^ 1] + r * 64 + s8 * 8);
      }
#pragma unroll
      for (int it = 0; it < 2; it++)
        vreg[it] = *(const int4*)(vg + base + (size_t)(kvn + it * 32 + strow) * E_DIM + s8 * 8);
    }

    // ---- S^T = K Q^T : T[m][n], col q = m*16+l15, row kv = n*16 + 4*l4 + i ----
    f32x4 T[2][4];
#pragma unroll
    for (int m = 0; m < 2; m++)
#pragma unroll
      for (int n = 0; n < 4; n++) T[m][n] = (f32x4){0.f, 0.f, 0.f, 0.f};
#pragma unroll
    for (int n = 0; n < 4; n++) {
      const int r = n * 16 + l15;
      const bf16v8 k0 = *(const bf16v8*)(sK[cur] + r * 64 + (l4 ^ (r & 7)) * 8);
      const bf16v8 k1 = *(const bf16v8*)(sK[cur] + r * 64 + ((4 + l4) ^ (r & 7)) * 8);
#pragma unroll
      for (int m = 0; m < 2; m++) {
        T[m][n] = __builtin_amdgcn_mfma_f32_16x16x32_bf16(k0, qf[m][0], T[m][n], 0, 0, 0);
        T[m][n] = __builtin_amdgcn_mfma_f32_16x16x32_bf16(k1, qf[m][1], T[m][n], 0, 0, 0);
      }
    }

    // ---- online softmax (log2 domain) with defer-max (THR = 8) ----
    float pm[2];
#pragma unroll
    for (int m = 0; m < 2; m++) {
      float mx = -1e30f;
#pragma unroll
      for (int n = 0; n < 4; n++)
        mx = fmaxf(mx, fmaxf(fmaxf(T[m][n][0], T[m][n][1]), fmaxf(T[m][n][2], T[m][n][3])));
      mx = fmaxf(mx, __shfl_xor(mx, 16));
      mx = fmaxf(mx, __shfl_xor(mx, 32));
      pm[m] = mx;
    }
    const bool skip = __all((pm[0] <= mrun[0] + 8.f) && (pm[1] <= mrun[1] + 8.f));
    unsigned W[2][4][2];
#pragma unroll
    for (int m = 0; m < 2; m++) {
      const float mnew = skip ? mrun[m] : fmaxf(mrun[m], pm[m]);
      float rsum = 0.f;
#pragma unroll
      for (int n = 0; n < 4; n++)
#pragma unroll
        for (int i = 0; i < 4; i++) {
          const float p = exp2f(T[m][n][i] - mnew);
          T[m][n][i] = p;
          rsum += p;
        }
      rsum += __shfl_xor(rsum, 16);
      rsum += __shfl_xor(rsum, 32);
      if (skip) {
        lrun[m] += rsum;
      } else {
        const float esc = exp2f(mrun[m] - mnew);
        mrun[m] = mnew;
        lrun[m] = lrun[m] * esc + rsum;
#pragma unroll
        for (int i = 0; i < 4; i++) {
          const float e = __shfl(esc, esrc + i);
#pragma unroll
          for (int nd = 0; nd < 4; nd++) acc_o[m][nd][i] *= e;
        }
      }
      // pack P pairs (kv 2p,2p+1 are i-contiguous in C-layout)
#pragma unroll
      for (int n = 0; n < 4; n++)
#pragma unroll
        for (int p = 0; p < 2; p++) {
          unsigned wv;
          asm("v_cvt_pk_bf16_f32 %0, %1, %2" : "=v"(wv) : "v"(T[m][n][2 * p]), "v"(T[m][n][2 * p + 1]));
          W[m][n][p] = wv;
        }
    }

    // ---- O += P V : pa rebuilt in-register via shfl; vb from swizzled sVt ----
#pragma unroll
    for (int kk = 0; kk < 2; kk++) {
      bf16v8 pa[2];
#pragma unroll
      for (int m = 0; m < 2; m++) {
        union { unsigned u[4]; bf16v8 v; } c;
#pragma unroll
        for (int wd = 0; wd < 4; wd++) {
          const int src = l15 + 16 * ((2 * l4 + (wd >> 1)) & 3);
          const unsigned a0 = __shfl(W[m][2 * kk][wd & 1], src);
          const unsigned a1 = __shfl(W[m][2 * kk + 1][wd & 1], src);
          c.u[wd] = (l4 < 2) ? a0 : a1;
        }
        pa[m] = c.v;
      }
#pragma unroll
      for (int nd = 0; nd < 4; nd++) {
        const int d = nd * 16 + l15;
        const int dsw = d ^ ((d >> 3) & 7);
        const bf16v8 vb = *(const bf16v8*)(sVt[cur] + (kk * 4 + l4) * 512 + dsw * 8);
#pragma unroll
        for (int m = 0; m < 2; m++)
          acc_o[m][nd] = __builtin_amdgcn_mfma_f32_16x16x32_bf16(pa[m], vb, acc_o[m][nd], 0, 0, 0);
      }
    }

    // ---- write tile t+1's V^T into the other buffer (vmcnt wait auto-inserted) ----
    if (t < 15) vt_write(sVt[cur ^ 1], vreg, strow, s8);
    __syncthreads();
  }

  // ---- epilogue: normalize rows, store ----
#pragma unroll
  for (int m = 0; m < 2; m++) {
    const float linv = 1.f / lrun[m];
#pragma unroll
    for (int i = 0; i < 4; i++) {
      const float li = __shfl(linv, esrc + i);
      const int s = qrow0 + m * 16 + l4 * 4 + i;
#pragma unroll
      for (int nd = 0; nd < 4; nd++)
        attn[base + (size_t)s * E_DIM + nd * 16 + l15] = f2b(acc_o[m][nd][i] * li);
    }
  }
}

// ---------------- LayerNorm (1 block = 1 row of 1024), ddof=1 ----------------
// MODE 0: y = 2*a  (ln1) ; MODE 1: y = a + b  (ln2)
template<int MODE>
__global__ __launch_bounds__(256) void ln_kernel(
    const float* __restrict__ a, const float* __restrict__ b2nd,
    const float* __restrict__ scale, const float* __restrict__ bias,
    float* __restrict__ outf, u16* __restrict__ outb) {
  const int row = blockIdx.x;
  const int tid = threadIdx.x;
  const size_t off = (size_t)row * 1024 + tid * 4;
  float4 v = *(const float4*)(a + off);
  if (MODE == 0) {
    v.x *= 2.f; v.y *= 2.f; v.z *= 2.f; v.w *= 2.f;
  } else {
    float4 u = *(const float4*)(b2nd + off);
    v.x += u.x; v.y += u.y; v.z += u.z; v.w += u.w;
  }
  float s = v.x + v.y + v.z + v.w;
  float q = v.x * v.x + v.y * v.y + v.z * v.z + v.w * v.w;
#pragma unroll
  for (int o = 1; o < 64; o <<= 1) { s += __shfl_xor(s, o); q += __shfl_xor(q, o); }
  __shared__ float red[8];
  const int wave = tid >> 6, lane = tid & 63;
  if (lane == 0) { red[wave] = s; red[4 + wave] = q; }
  __syncthreads();
  s = red[0] + red[1] + red[2] + red[3];
  q = red[4] + red[5] + red[6] + red[7];
  const float mean = s * (1.f / 1024.f);
  const float var = (q - 1024.f * mean * mean) * (1.f / 1023.f);
  const float rstd = rsqrtf(var + 1e-5f);
  const int c = tid * 4;
  float4 sc = *(const float4*)(scale + c);
  float4 bi = *(const float4*)(bias + c);
  float4 o;
  o.x = sc.x * (v.x - mean) * rstd + bi.x;
  o.y = sc.y * (v.y - mean) * rstd + bi.y;
  o.z = sc.z * (v.z - mean) * rstd + bi.z;
  o.w = sc.w * (v.w - mean) * rstd + bi.w;
  *(float4*)(outf + off) = o;
  if (outb != nullptr) {
    ushort4 ob;
    ob.x = f2b(o.x); ob.y = f2b(o.y); ob.z = f2b(o.z); ob.w = f2b(o.w);
    *(ushort4*)(outb + off) = ob;
  }
}

// ---------------- fp32 -> bf16 cast (4 elems/thread) ----------------
__global__ __launch_bounds__(256) void cast_bf16_k(const float* __restrict__ in,
                                                   u16* __restrict__ out, int n4) {
  const int i = blockIdx.x * blockDim.x + threadIdx.x;
  if (i >= n4) return;
  float4 v = *(const float4*)(in + (size_t)i * 4);
  ushort4 o;
  o.x = f2b(v.x); o.y = f2b(v.y); o.z = f2b(v.z); o.w = f2b(v.w);
  *(ushort4*)(out + (size_t)i * 4) = o;
}

// ---------------- 1024x1024 fp32 transpose + bf16 cast ----------------
__global__ __launch_bounds__(256) void transpose_cast_k(const float* __restrict__ in,
                                                        u16* __restrict__ out) {
  __shared__ float tile[32][33];
  const int tx = threadIdx.x & 31, ty = threadIdx.x >> 5;
  const int bx = blockIdx.x * 32, by = blockIdx.y * 32;
#pragma unroll
  for (int j = 0; j < 4; j++)
    tile[ty + j * 8][tx] = in[(size_t)(by + ty + j * 8) * 1024 + bx + tx];
  __syncthreads();
#pragma unroll
  for (int j = 0; j < 4; j++)
    out[(size_t)(bx + ty + j * 8) * 1024 + by + tx] = f2b(tile[tx][ty + j * 8]);
}

extern "C" void kernel_launch(void* const* d_in, const int* in_sizes, int n_in,
                              void* d_out, int out_size, void* d_ws, size_t ws_size,
                              hipStream_t stream) {
  const float* x    = (const float*)d_in[0];
  const float* in_w = (const float*)d_in[1];
  const float* out_w = (const float*)d_in[2];
  const float* ln1s = (const float*)d_in[3];
  const float* ln1b = (const float*)d_in[4];
  const float* ln2s = (const float*)d_in[5];
  const float* ln2b = (const float*)d_in[6];
  const float* w1   = (const float*)d_in[7];
  const float* b1   = (const float*)d_in[8];
  const float* w2   = (const float*)d_in[9];
  const float* b2   = (const float*)d_in[10];
  float* outp = (float*)d_out;

  char* ws = (char*)d_ws;
  u16*   xb    = (u16*)(ws + 0);            // 16.78MB  -> attn (alias) -> H (alias)
  u16*   qb    = (u16*)(ws + 16777216);     // 16.78MB  -> attn_out f32 (alias) -> H
  u16*   kbuf  = (u16*)(ws + 33554432);     // 16.78MB
  u16*   vbuf  = (u16*)(ws + 50331648);     // 16.78MB
  u16*   attnb = xb;
  float* attno = (float*)(ws + 16777216);   // 33.55MB (over dead q,k)
  u16*   Hb    = (u16*)(ws + 0);            // 67.11MB (over dead xb/attn,q,k,v)
  float* x1f   = (float*)(ws + 67108864);   // 33.55MB
  u16*   x1b   = (u16*)(ws + 100663296);    // 16.78MB
  float* ffn   = (float*)(ws + 117440512);  // 33.55MB
  u16*   wkt   = (u16*)(ws + 150994944);    // weights: 4x2MB + 2x8.39MB
  u16*   wqt   = wkt + 1048576;
  u16*   wvt   = wqt + 1048576;
  u16*   wot   = wvt + 1048576;
  u16*   w1b   = wot + 1048576;
  u16*   w2b   = w1b + 4194304;
  (void)ws_size; (void)in_sizes; (void)n_in; (void)out_size;

  // casts / transposes
  cast_bf16_k<<<8192, 256, 0, stream>>>(x, xb, 2097152);
  cast_bf16_k<<<4096, 256, 0, stream>>>(w1, w1b, 1048576);
  cast_bf16_k<<<4096, 256, 0, stream>>>(w2, w2b, 1048576);
  dim3 tg(32, 32);
  transpose_cast_k<<<tg, 256, 0, stream>>>(in_w + 0,       wkt);  // k uses in_weights[0]
  transpose_cast_k<<<tg, 256, 0, stream>>>(in_w + 1048576, wqt);  // q uses in_weights[1]
  transpose_cast_k<<<tg, 256, 0, stream>>>(in_w + 2097152, wvt);  // v uses in_weights[2]
  transpose_cast_k<<<tg, 256, 0, stream>>>(out_w,          wot);

  // QKV projections (Q pre-scaled by 0.125*log2e for exp2-domain softmax)
  dim3 g1(8, 64);
  gemm_bt<4><<<g1, 256, 0, stream>>>(xb, wqt, qb,   nullptr, NROWS, 1024, 1024);
  gemm_bt<1><<<g1, 256, 0, stream>>>(xb, wkt, kbuf, nullptr, NROWS, 1024, 1024);
  gemm_bt<1><<<g1, 256, 0, stream>>>(xb, wvt, vbuf, nullptr, NROWS, 1024, 1024);

  // attention
  attn_fa<<<1024, 256, 0, stream>>>(qb, kbuf, vbuf, attnb);

  // output projection
  gemm_bt<0><<<g1, 256, 0, stream>>>(attnb, wot, attno, nullptr, NROWS, 1024, 1024);

  // ln1: x1 = LN(2*attn_out)
  ln_kernel<0><<<8192, 256, 0, stream>>>(attno, nullptr, ln1s, ln1b, x1f, x1b);

  // FFN
  dim3 g2(32, 64);
  gemm_bt<2><<<g2, 256, 0, stream>>>(x1b, w1b, Hb, b1, NROWS, 4096, 1024);
  gemm_bt<3><<<g1, 256, 0, stream>>>(Hb, w2b, ffn, b2, NROWS, 1024, 4096);

  // ln2: out = LN(x1 + ffn)
  ln_kernel<1><<<8192, 256, 0, stream>>>(x1f, ffn, ln2s, ln2b, outp, nullptr);
}

// Round 4
// 415.768 us; speedup vs baseline: 1.3986x; 1.1237x over previous
//
#include <hip/hip_runtime.h>

#define E_DIM 1024
#define S_LEN 1024
#define H_NUM 16
#define HD_DIM 64
#define B_NUM 8
#define DFF_DIM 4096
#define NROWS 8192   // B*S
#define QKV_LD 3072  // fused qkv row stride

typedef unsigned short u16;
typedef short bf16v8 __attribute__((ext_vector_type(8)));
typedef float f32x4 __attribute__((ext_vector_type(4)));

// softmax scale folded into Q projection: 1/sqrt(64) * log2(e)
#define QK_SCALE 0.18033688011112042f

__device__ __forceinline__ u16 f2b(float f) {
  union { float f; unsigned u; } x; x.f = f;
  return (u16)((x.u + 0x7fffu + ((x.u >> 16) & 1u)) >> 16);
}

__device__ __forceinline__ void gload16(const void* g, void* l) {
  __builtin_amdgcn_global_load_lds((const __attribute__((address_space(1))) void*)g,
                                   (__attribute__((address_space(3))) void*)l, 16, 0, 0);
}

// ================= 8-phase-style GEMM, BM=BN=256, BK=64, 512 thr, 8 waves =================
// C[M=8192, N] = A[.,K-span] * Bt[N][K-span]^T   (bf16 in, per-MODE epilogue)
// MODE 0: bf16 out, cols [1024,2048) scaled by QK_SCALE (fused QKV).
// MODE 1: f32 partial out (split-K: kh ? C1 : C0), no bias.        (Wo)
// MODE 2: bf16 out + bias + relu.                                   (FFN1)
// MODE 3: f32 partial out + bias only on kh==0.                     (FFN2)
// Schedule per K-tile t (4 phases), frags read one phase ahead, counted vmcnt:
//  p0: stage L6-7(t+1) | MFMA(mh0,n01) | ds_read b23(t)    | bar
//  p1:                   MFMA(mh0,n23) | ds_read a(mh1,t)  | bar
//  p2: stage L0-2(t+2) | MFMA(mh1,n01) | vmcnt(3)          | bar   <- validates tile t+1
//  p3: stage L3-5(t+2) | MFMA(mh1,n23) | ds_read a(mh0),b01 @ t+1 | bar
template<int MODE>
__global__ __launch_bounds__(512, 2) void gemm8(
    const u16* __restrict__ A, const u16* __restrict__ Bt,
    void* __restrict__ C0, void* __restrict__ C1, const float* __restrict__ bias,
    int N, int KA, int nxt, int NT) {
  __shared__ u16 sA[2 * 16384];
  __shared__ u16 sB[2 * 16384];

  const int tid = threadIdx.x;
  const int lane = tid & 63;
  const int wid = tid >> 6;
  const int wm = wid >> 2, wn = wid & 3;
  const int l15 = lane & 15, l4 = lane >> 4;
  const int pk0 = l4 ^ (l15 & 7);

  // XCD-aware swizzle over full grid, then decompose (x = nxt * ksplit)
  const int gx = gridDim.x;
  const int lin = blockIdx.y * gx + blockIdx.x;
  const int chunk = (gx * gridDim.y) >> 3;
  const int swz = (lin & 7) * chunk + (lin >> 3);
  const int bym = swz / gx, bxm = swz % gx;
  const int kh = (bxm >= nxt) ? 1 : 0;
  const int bm = bym * 256;
  const int bn = (bxm - kh * nxt) * 256;
  const int k0 = kh * NT * 64;

  // staging pointers: load li<4 -> A row i*64+(tid>>3); li>=4 -> B same rows.
  // linear LDS chunk (tid&7) holds global chunk (tid&7)^(row&7) (XOR swizzle).
  const int srow = tid >> 3;
  const int gch = ((tid & 7) ^ (srow & 7)) * 8;
  const u16* Ag[4];
  const u16* Bg[4];
#pragma unroll
  for (int i = 0; i < 4; ++i) {
    Ag[i] = A + k0 + (size_t)(bm + i * 64 + srow) * KA + gch;
    Bg[i] = Bt + k0 + (size_t)(bn + i * 64 + srow) * KA + gch;
  }
  const int t8 = tid * 8;

#define ST1(tile, li)                                                              \
  do {                                                                             \
    if ((li) < 4) gload16(Ag[li] + (tile) * 64, sA + ((tile)&1) * 16384 + (li)*4096 + t8); \
    else gload16(Bg[(li)-4] + (tile) * 64, sB + ((tile)&1) * 16384 + ((li)-4) * 4096 + t8); \
  } while (0)
#define STG(tile, lo, hi)                                  \
  if ((tile) < NT) {                                       \
    _Pragma("unroll") for (int li = (lo); li <= (hi); ++li) ST1(tile, li); \
  }

  bf16v8 a[4][2], b[4][2];
  f32x4 acc[8][4];
#pragma unroll
  for (int m = 0; m < 8; ++m)
#pragma unroll
    for (int n = 0; n < 4; ++n) acc[m][n] = (f32x4){0.f, 0.f, 0.f, 0.f};

#define LDA(mh, buf)                                                        \
  {                                                                         \
    _Pragma("unroll") for (int mp = 0; mp < 4; ++mp) {                      \
      const u16* rp = (buf) + (size_t)(wm * 128 + (mh)*64 + mp * 16 + l15) * 64; \
      a[mp][0] = *(const bf16v8*)(rp + pk0 * 8);                            \
      a[mp][1] = *(const bf16v8*)(rp + (pk0 ^ 4) * 8);                      \
    }                                                                       \
  }
#define LDB(n0, buf)                                                        \
  {                                                                         \
    _Pragma("unroll") for (int nn = (n0); nn < (n0) + 2; ++nn) {            \
      const u16* rp = (buf) + (size_t)(wn * 64 + nn * 16 + l15) * 64;       \
      b[nn][0] = *(const bf16v8*)(rp + pk0 * 8);                            \
      b[nn][1] = *(const bf16v8*)(rp + (pk0 ^ 4) * 8);                      \
    }                                                                       \
  }
#define MMPH(mh, n0)                                                                      \
  {                                                                                       \
    __builtin_amdgcn_s_setprio(1);                                                        \
    _Pragma("unroll") for (int mp = 0; mp < 4; ++mp) {                                    \
      _Pragma("unroll") for (int nn = (n0); nn < (n0) + 2; ++nn) {                        \
        acc[(mh)*4 + mp][nn] = __builtin_amdgcn_mfma_f32_16x16x32_bf16(                   \
            a[mp][0], b[nn][0], acc[(mh)*4 + mp][nn], 0, 0, 0);                           \
        acc[(mh)*4 + mp][nn] = __builtin_amdgcn_mfma_f32_16x16x32_bf16(                   \
            a[mp][1], b[nn][1], acc[(mh)*4 + mp][nn], 0, 0, 0);                           \
      }                                                                                   \
    }                                                                                     \
    __builtin_amdgcn_s_setprio(0);                                                        \
  }

  // ---- prologue: tile0 fully + tile1 L0-5; validate tile0; pre-read its frags ----
#pragma unroll
  for (int li = 0; li < 8; ++li) ST1(0, li);
  STG(1, 0, 5);
  __builtin_amdgcn_sched_barrier(0);
  asm volatile("s_waitcnt vmcnt(6)" ::: "memory");
  __builtin_amdgcn_s_barrier();
  LDA(0, sA);
  LDB(0, sB);

  for (int t = 0; t < NT; ++t) {
    u16* sAc = sA + (t & 1) * 16384;
    u16* sBc = sB + (t & 1) * 16384;
    u16* sAn = sA + ((t + 1) & 1) * 16384;
    u16* sBn = sB + ((t + 1) & 1) * 16384;
    // ---- p0 ----
    STG(t + 1, 6, 7);
    MMPH(0, 0);
    LDB(2, sBc);
    __builtin_amdgcn_s_barrier();
    // ---- p1 ----
    MMPH(0, 2);
    LDA(1, sAc);
    __builtin_amdgcn_s_barrier();
    // ---- p2 ----
    STG(t + 2, 0, 2);
    MMPH(1, 0);
    __builtin_amdgcn_sched_barrier(0);
    if (t + 1 < NT) {
      if (t + 2 < NT) asm volatile("s_waitcnt vmcnt(3)" ::: "memory");
      else            asm volatile("s_waitcnt vmcnt(0)" ::: "memory");
    }
    __builtin_amdgcn_s_barrier();
    // ---- p3 ----
    STG(t + 2, 3, 5);
    MMPH(1, 2);
    if (t + 1 < NT) {
      LDA(0, sAn);
      LDB(0, sBn);
    }
    __builtin_amdgcn_s_barrier();
  }

  // ---- epilogue ----
  const int lrow0 = bm + wm * 128 + l4 * 4;
  const int lcol0 = bn + wn * 64 + l15;
  const float scl = (MODE == 0 && ((bn >> 10) == 1)) ? QK_SCALE : 1.f;
  void* Cw = kh ? C1 : C0;
#pragma unroll
  for (int m = 0; m < 8; ++m) {
#pragma unroll
    for (int n = 0; n < 4; ++n) {
      const int col = lcol0 + n * 16;
      float bv = 0.f;
      if (MODE == 2) bv = bias[col];
      if (MODE == 3) bv = kh ? 0.f : bias[col];
#pragma unroll
      for (int i = 0; i < 4; ++i) {
        const int row = lrow0 + m * 16 + i;
        float v = acc[m][n][i] + bv;
        if (MODE == 2) v = fmaxf(v, 0.f);
        if (MODE == 0) v *= scl;
        if (MODE == 0 || MODE == 2)
          ((u16*)Cw)[(size_t)row * N + col] = f2b(v);
        else
          ((float*)Cw)[(size_t)row * N + col] = v;
      }
    }
  }
#undef ST1
#undef STG
#undef LDA
#undef LDB
#undef MMPH
}

// V^T staging: pair rows via shfl_xor(8), pack kv-pairs into u32 writes.
// Layout: sVt[kv>>3][d ^ ((d>>3)&7)][kv&7]
__device__ __forceinline__ void vt_write(u16* sVtBuf, const int4* vr, int strow, int s8) {
#pragma unroll
  for (int it = 0; it < 2; it++) {
    const int r = it * 32 + strow;
    int4 wv = vr[it];
    int4 w2;
    w2.x = __shfl_xor(wv.x, 8); w2.y = __shfl_xor(wv.y, 8);
    w2.z = __shfl_xor(wv.z, 8); w2.w = __shfl_xor(wv.w, 8);
    const int t = r >> 1;
    const int odd = r & 1;
    const u16* own = (const u16*)&wv;
    const u16* par = (const u16*)&w2;
    char* dstbase = (char*)sVtBuf + (t >> 2) * 1024 + (t & 3) * 4;
#pragma unroll
    for (int k = 0; k < 4; k++) {
      const unsigned lo = odd ? (unsigned)par[4 + k] : (unsigned)own[k];
      const unsigned hi = odd ? (unsigned)own[4 + k] : (unsigned)par[k];
      const int d = s8 * 8 + k + (odd ? 4 : 0);
      const int dsw = d ^ s8;  // d>>3 == s8
      *(unsigned*)(dstbase + dsw * 16) = lo | (hi << 16);
    }
  }
}

// ---------------- Flash attention, swapped-QK^T + async double-buffer ----------------
// Inputs from fused qkv buffer [8192][3072]: k cols 0-1023, q 1024-2047, v 2048-3071.
__global__ __launch_bounds__(256) void attn_fa(
    const u16* __restrict__ qkv, u16* __restrict__ attn) {
  __shared__ u16 sK[2][64 * 64];
  __shared__ u16 sVt[2][64 * 64];

  const int tid = threadIdx.x, lane = tid & 63, wave = tid >> 6;
  const int l15 = lane & 15, l4 = lane >> 4;
  const int w = ((blockIdx.x & 7) << 7) + (blockIdx.x >> 3);  // XCD swizzle
  const int bh = w >> 3;
  const int b = bh >> 4, h = bh & 15;
  const int qrow0 = (w & 7) * 128 + wave * 32;
  const size_t rowb = (size_t)b * S_LEN * QKV_LD;
  const u16* kg = qkv + rowb + h * HD_DIM;
  const u16* qg = qkv + rowb + 1024 + h * HD_DIM;
  const u16* vg = qkv + rowb + 2048 + h * HD_DIM;
  const size_t obase = (size_t)b * (S_LEN * E_DIM) + (size_t)h * HD_DIM;
  const int esrc = (lane & 48) + l4 * 4;

  bf16v8 qf[2][2];
#pragma unroll
  for (int m = 0; m < 2; m++)
#pragma unroll
    for (int kk = 0; kk < 2; kk++)
      qf[m][kk] = *(const bf16v8*)(qg + (size_t)(qrow0 + m * 16 + l15) * QKV_LD + kk * 32 + l4 * 8);

  f32x4 acc_o[2][4];
  float mrun[2], lrun[2];
#pragma unroll
  for (int m = 0; m < 2; m++) {
    mrun[m] = -1e30f; lrun[m] = 0.f;
#pragma unroll
    for (int nd = 0; nd < 4; nd++) acc_o[m][nd] = (f32x4){0.f, 0.f, 0.f, 0.f};
  }

  const int strow = tid >> 3;
  const int s8 = tid & 7;

  {
#pragma unroll
    for (int it = 0; it < 2; it++) {
      const int r = it * 32 + strow;
      gload16(kg + (size_t)r * QKV_LD + (s8 ^ (r & 7)) * 8, sK[0] + r * 64 + s8 * 8);
    }
    int4 v0[2];
#pragma unroll
    for (int it = 0; it < 2; it++)
      v0[it] = *(const int4*)(vg + (size_t)(it * 32 + strow) * QKV_LD + s8 * 8);
    vt_write(sVt[0], v0, strow, s8);
    __syncthreads();
  }

  for (int t = 0; t < 16; t++) {
    const int cur = t & 1;
    int4 vreg[2];
    if (t < 15) {
      const int kvn = (t + 1) * 64;
#pragma unroll
      for (int it = 0; it < 2; it++) {
        const int r = it * 32 + strow;
        gload16(kg + (size_t)(kvn + r) * QKV_LD + (s8 ^ (r & 7)) * 8,
                sK[cur ^ 1] + r * 64 + s8 * 8);
      }
#pragma unroll
      for (int it = 0; it < 2; it++)
        vreg[it] = *(const int4*)(vg + (size_t)(kvn + it * 32 + strow) * QKV_LD + s8 * 8);
    }

    f32x4 T[2][4];
#pragma unroll
    for (int m = 0; m < 2; m++)
#pragma unroll
      for (int n = 0; n < 4; n++) T[m][n] = (f32x4){0.f, 0.f, 0.f, 0.f};
#pragma unroll
    for (int n = 0; n < 4; n++) {
      const int r = n * 16 + l15;
      const bf16v8 k0 = *(const bf16v8*)(sK[cur] + r * 64 + (l4 ^ (r & 7)) * 8);
      const bf16v8 k1 = *(const bf16v8*)(sK[cur] + r * 64 + ((4 + l4) ^ (r & 7)) * 8);
#pragma unroll
      for (int m = 0; m < 2; m++) {
        T[m][n] = __builtin_amdgcn_mfma_f32_16x16x32_bf16(k0, qf[m][0], T[m][n], 0, 0, 0);
        T[m][n] = __builtin_amdgcn_mfma_f32_16x16x32_bf16(k1, qf[m][1], T[m][n], 0, 0, 0);
      }
    }

    float pm[2];
#pragma unroll
    for (int m = 0; m < 2; m++) {
      float mx = -1e30f;
#pragma unroll
      for (int n = 0; n < 4; n++)
        mx = fmaxf(mx, fmaxf(fmaxf(T[m][n][0], T[m][n][1]), fmaxf(T[m][n][2], T[m][n][3])));
      mx = fmaxf(mx, __shfl_xor(mx, 16));
      mx = fmaxf(mx, __shfl_xor(mx, 32));
      pm[m] = mx;
    }
    const bool skip = __all((pm[0] <= mrun[0] + 8.f) && (pm[1] <= mrun[1] + 8.f));
    unsigned W[2][4][2];
#pragma unroll
    for (int m = 0; m < 2; m++) {
      const float mnew = skip ? mrun[m] : fmaxf(mrun[m], pm[m]);
      float rsum = 0.f;
#pragma unroll
      for (int n = 0; n < 4; n++)
#pragma unroll
        for (int i = 0; i < 4; i++) {
          const float p = exp2f(T[m][n][i] - mnew);
          T[m][n][i] = p;
          rsum += p;
        }
      rsum += __shfl_xor(rsum, 16);
      rsum += __shfl_xor(rsum, 32);
      if (skip) {
        lrun[m] += rsum;
      } else {
        const float esc = exp2f(mrun[m] - mnew);
        mrun[m] = mnew;
        lrun[m] = lrun[m] * esc + rsum;
#pragma unroll
        for (int i = 0; i < 4; i++) {
          const float e = __shfl(esc, esrc + i);
#pragma unroll
          for (int nd = 0; nd < 4; nd++) acc_o[m][nd][i] *= e;
        }
      }
#pragma unroll
      for (int n = 0; n < 4; n++)
#pragma unroll
        for (int p = 0; p < 2; p++) {
          unsigned wv;
          asm("v_cvt_pk_bf16_f32 %0, %1, %2" : "=v"(wv) : "v"(T[m][n][2 * p]), "v"(T[m][n][2 * p + 1]));
          W[m][n][p] = wv;
        }
    }

#pragma unroll
    for (int kk = 0; kk < 2; kk++) {
      bf16v8 pa[2];
#pragma unroll
      for (int m = 0; m < 2; m++) {
        union { unsigned u[4]; bf16v8 v; } c;
#pragma unroll
        for (int wd = 0; wd < 4; wd++) {
          const int src = l15 + 16 * ((2 * l4 + (wd >> 1)) & 3);
          const unsigned a0 = __shfl(W[m][2 * kk][wd & 1], src);
          const unsigned a1 = __shfl(W[m][2 * kk + 1][wd & 1], src);
          c.u[wd] = (l4 < 2) ? a0 : a1;
        }
        pa[m] = c.v;
      }
#pragma unroll
      for (int nd = 0; nd < 4; nd++) {
        const int d = nd * 16 + l15;
        const int dsw = d ^ ((d >> 3) & 7);
        const bf16v8 vb = *(const bf16v8*)(sVt[cur] + (kk * 4 + l4) * 512 + dsw * 8);
#pragma unroll
        for (int m = 0; m < 2; m++)
          acc_o[m][nd] = __builtin_amdgcn_mfma_f32_16x16x32_bf16(pa[m], vb, acc_o[m][nd], 0, 0, 0);
      }
    }

    if (t < 15) vt_write(sVt[cur ^ 1], vreg, strow, s8);
    __syncthreads();
  }

#pragma unroll
  for (int m = 0; m < 2; m++) {
    const float linv = 1.f / lrun[m];
#pragma unroll
    for (int i = 0; i < 4; i++) {
      const float li = __shfl(linv, esrc + i);
      const int s = qrow0 + m * 16 + l4 * 4 + i;
#pragma unroll
      for (int nd = 0; nd < 4; nd++)
        attn[obase + (size_t)s * E_DIM + nd * 16 + l15] = f2b(acc_o[m][nd][i] * linv * 0.f + f2b(0.f) * 0.f + acc_o[m][nd][i] * li);
    }
  }
}

// ---------------- LayerNorm (1 block = 1 row of 1024), ddof=1 ----------------
// MODE 0: y = 2*(a+b)  (ln1, Wo split-K partials) ; MODE 1: y = a+b+c  (ln2)
template<int MODE>
__global__ __launch_bounds__(256) void ln_kernel(
    const float* __restrict__ a, const float* __restrict__ b2nd, const float* __restrict__ c3rd,
    const float* __restrict__ scale, const float* __restrict__ bias,
    float* __restrict__ outf, u16* __restrict__ outb) {
  const int row = blockIdx.x;
  const int tid = threadIdx.x;
  const size_t off = (size_t)row * 1024 + tid * 4;
  float4 v = *(const float4*)(a + off);
  float4 u = *(const float4*)(b2nd + off);
  if (MODE == 0) {
    v.x = 2.f * (v.x + u.x); v.y = 2.f * (v.y + u.y);
    v.z = 2.f * (v.z + u.z); v.w = 2.f * (v.w + u.w);
  } else {
    float4 w = *(const float4*)(c3rd + off);
    v.x += u.x + w.x; v.y += u.y + w.y; v.z += u.z + w.z; v.w += u.w + w.w;
  }
  float s = v.x + v.y + v.z + v.w;
  float q = v.x * v.x + v.y * v.y + v.z * v.z + v.w * v.w;
#pragma unroll
  for (int o = 1; o < 64; o <<= 1) { s += __shfl_xor(s, o); q += __shfl_xor(q, o); }
  __shared__ float red[8];
  const int wave = tid >> 6, lane = tid & 63;
  if (lane == 0) { red[wave] = s; red[4 + wave] = q; }
  __syncthreads();
  s = red[0] + red[1] + red[2] + red[3];
  q = red[4] + red[5] + red[6] + red[7];
  const float mean = s * (1.f / 1024.f);
  const float var = (q - 1024.f * mean * mean) * (1.f / 1023.f);
  const float rstd = rsqrtf(var + 1e-5f);
  const int c = tid * 4;
  float4 sc = *(const float4*)(scale + c);
  float4 bi = *(const float4*)(bias + c);
  float4 o;
  o.x = sc.x * (v.x - mean) * rstd + bi.x;
  o.y = sc.y * (v.y - mean) * rstd + bi.y;
  o.z = sc.z * (v.z - mean) * rstd + bi.z;
  o.w = sc.w * (v.w - mean) * rstd + bi.w;
  *(float4*)(outf + off) = o;
  if (outb != nullptr) {
    ushort4 ob;
    ob.x = f2b(o.x); ob.y = f2b(o.y); ob.z = f2b(o.z); ob.w = f2b(o.w);
    *(ushort4*)(outb + off) = ob;
  }
}

// ---------------- fp32 -> bf16 cast (4 elems/thread) ----------------
__global__ __launch_bounds__(256) void cast_bf16_k(const float* __restrict__ in,
                                                   u16* __restrict__ out, int n4) {
  const int i = blockIdx.x * blockDim.x + threadIdx.x;
  if (i >= n4) return;
  float4 v = *(const float4*)(in + (size_t)i * 4);
  ushort4 o;
  o.x = f2b(v.x); o.y = f2b(v.y); o.z = f2b(v.z); o.w = f2b(v.w);
  *(ushort4*)(out + (size_t)i * 4) = o;
}

// ---------------- 1024x1024 fp32 transpose + bf16 cast ----------------
__global__ __launch_bounds__(256) void transpose_cast_k(const float* __restrict__ in,
                                                        u16* __restrict__ out) {
  __shared__ float tile[32][33];
  const int tx = threadIdx.x & 31, ty = threadIdx.x >> 5;
  const int bx = blockIdx.x * 32, by = blockIdx.y * 32;
#pragma unroll
  for (int j = 0; j < 4; j++)
    tile[ty + j * 8][tx] = in[(size_t)(by + ty + j * 8) * 1024 + bx + tx];
  __syncthreads();
#pragma unroll
  for (int j = 0; j < 4; j++)
    out[(size_t)(bx + ty + j * 8) * 1024 + by + tx] = f2b(tile[tx][ty + j * 8]);
}

extern "C" void kernel_launch(void* const* d_in, const int* in_sizes, int n_in,
                              void* d_out, int out_size, void* d_ws, size_t ws_size,
                              hipStream_t stream) {
  const float* x    = (const float*)d_in[0];
  const float* in_w = (const float*)d_in[1];
  const float* out_w = (const float*)d_in[2];
  const float* ln1s = (const float*)d_in[3];
  const float* ln1b = (const float*)d_in[4];
  const float* ln2s = (const float*)d_in[5];
  const float* ln2b = (const float*)d_in[6];
  const float* w1   = (const float*)d_in[7];
  const float* b1   = (const float*)d_in[8];
  const float* w2   = (const float*)d_in[9];
  const float* b2   = (const float*)d_in[10];
  float* outp = (float*)d_out;

  char* ws = (char*)d_ws;
  // arena (peak 176,160,768 B, same as prior rounds):
  u16*   xb    = (u16*)(ws + 0);            // 16.8M; dead after QKV gemm
  u16*   qkv   = (u16*)(ws + 16777216);     // 50.3M [8192][3072]; dead after attn
  u16*   attnb = (u16*)(ws + 0);            // 16.8M over dead xb; dead after Wo
  float* attno0 = (float*)(ws + 67108864);  // 33.5M; dead after ln1
  float* attno1 = (float*)(ws + 100663296); // 33.5M; dead after ln1
  float* x1f   = (float*)(ws + 67108864);   // in-place over attno0 (row-local)
  u16*   x1b   = (u16*)(ws + 134217728);    // 16.8M; dead after FFN1
  u16*   Hb    = (u16*)(ws + 0);            // 67.1M over dead xb/qkv/attnb
  float* ffn0  = (float*)(ws + 100663296);  // over dead attno1
  // ffn partial 1 -> d_out (scratch until ln2 rewrites it)
  u16*   wkt   = (u16*)(ws + 150994944);    // [3072][1024] concat k,q,v transposed
  u16*   wot   = wkt + 3145728;
  u16*   w1b   = wot + 1048576;
  u16*   w2b   = w1b + 4194304;
  (void)ws_size; (void)in_sizes; (void)n_in; (void)out_size;

  // casts / transposes
  cast_bf16_k<<<8192, 256, 0, stream>>>(x, xb, 2097152);
  cast_bf16_k<<<4096, 256, 0, stream>>>(w1, w1b, 1048576);
  cast_bf16_k<<<4096, 256, 0, stream>>>(w2, w2b, 1048576);
  dim3 tg(32, 32);
  transpose_cast_k<<<tg, 256, 0, stream>>>(in_w + 0,       wkt);            // k
  transpose_cast_k<<<tg, 256, 0, stream>>>(in_w + 1048576, wkt + 1048576); // q
  transpose_cast_k<<<tg, 256, 0, stream>>>(in_w + 2097152, wkt + 2097152); // v
  transpose_cast_k<<<tg, 256, 0, stream>>>(out_w,          wot);

  // fused QKV projection: [8192][3072], q block scaled by QK_SCALE
  gemm8<0><<<dim3(12, 32), 512, 0, stream>>>(xb, wkt, qkv, nullptr, nullptr, 3072, 1024, 12, 16);

  // attention
  attn_fa<<<1024, 256, 0, stream>>>(qkv, attnb);

  // output projection, split-K=2 -> two f32 partials
  gemm8<1><<<dim3(8, 32), 512, 0, stream>>>(attnb, wot, attno0, attno1, nullptr, 1024, 1024, 4, 8);

  // ln1: x1 = LN(2*(attno0+attno1))
  ln_kernel<0><<<8192, 256, 0, stream>>>(attno0, attno1, nullptr, ln1s, ln1b, x1f, x1b);

  // FFN1: bf16 + bias + relu
  gemm8<2><<<dim3(16, 32), 512, 0, stream>>>(x1b, w1b, Hb, nullptr, b1, 4096, 1024, 16, 16);

  // FFN2: split-K=2, partial0 -> ffn0 (+bias), partial1 -> d_out scratch
  gemm8<3><<<dim3(8, 32), 512, 0, stream>>>(Hb, w2b, ffn0, outp, b2, 1024, 4096, 4, 32);

  // ln2: out = LN(x1 + ffn0 + ffn1)
  ln_kernel<1><<<8192, 256, 0, stream>>>(x1f, ffn0, outp, ln2s, ln2b, outp, nullptr);
}

// Round 6
// 386.109 us; speedup vs baseline: 1.5060x; 1.0768x over previous
//
#include <hip/hip_runtime.h>

#define E_DIM 1024
#define S_LEN 1024
#define H_NUM 16
#define HD_DIM 64
#define B_NUM 8
#define DFF_DIM 4096
#define NROWS 8192   // B*S
#define QKV_LD 3072  // fused qkv row stride

typedef unsigned short u16;
typedef unsigned u32;
typedef short bf16v8 __attribute__((ext_vector_type(8)));
typedef float f32x4 __attribute__((ext_vector_type(4)));
typedef float f32x16 __attribute__((ext_vector_type(16)));

// softmax scale folded into Q projection: 1/sqrt(64) * log2(e)
#define QK_SCALE 0.18033688011112042f

__device__ __forceinline__ u16 f2b(float f) {
  union { float f; unsigned u; } x; x.f = f;
  return (u16)((x.u + 0x7fffu + ((x.u >> 16) & 1u)) >> 16);
}

__device__ __forceinline__ void gload16(const void* g, void* l) {
  __builtin_amdgcn_global_load_lds((const __attribute__((address_space(1))) void*)g,
                                   (__attribute__((address_space(3))) void*)l, 16, 0, 0);
}

// ================= 8-phase-style GEMM, BM=BN=256, BK=64, 512 thr, 8 waves =================
// (unchanged from R4 — verified)
template<int MODE>
__global__ __launch_bounds__(512, 2) void gemm8(
    const u16* __restrict__ A, const u16* __restrict__ Bt,
    void* __restrict__ C0, void* __restrict__ C1, const float* __restrict__ bias,
    int N, int KA, int nxt, int NT) {
  __shared__ u16 sA[2 * 16384];
  __shared__ u16 sB[2 * 16384];

  const int tid = threadIdx.x;
  const int lane = tid & 63;
  const int wid = tid >> 6;
  const int wm = wid >> 2, wn = wid & 3;
  const int l15 = lane & 15, l4 = lane >> 4;
  const int pk0 = l4 ^ (l15 & 7);

  const int gx = gridDim.x;
  const int lin = blockIdx.y * gx + blockIdx.x;
  const int chunk = (gx * gridDim.y) >> 3;
  const int swz = (lin & 7) * chunk + (lin >> 3);
  const int bym = swz / gx, bxm = swz % gx;
  const int kh = (bxm >= nxt) ? 1 : 0;
  const int bm = bym * 256;
  const int bn = (bxm - kh * nxt) * 256;
  const int k0 = kh * NT * 64;

  const int srow = tid >> 3;
  const int gch = ((tid & 7) ^ (srow & 7)) * 8;
  const u16* Ag[4];
  const u16* Bg[4];
#pragma unroll
  for (int i = 0; i < 4; ++i) {
    Ag[i] = A + k0 + (size_t)(bm + i * 64 + srow) * KA + gch;
    Bg[i] = Bt + k0 + (size_t)(bn + i * 64 + srow) * KA + gch;
  }
  const int t8 = tid * 8;

#define ST1(tile, li)                                                              \
  do {                                                                             \
    if ((li) < 4) gload16(Ag[li] + (tile) * 64, sA + ((tile)&1) * 16384 + (li)*4096 + t8); \
    else gload16(Bg[(li)-4] + (tile) * 64, sB + ((tile)&1) * 16384 + ((li)-4) * 4096 + t8); \
  } while (0)
#define STG(tile, lo, hi)                                  \
  if ((tile) < NT) {                                       \
    _Pragma("unroll") for (int li = (lo); li <= (hi); ++li) ST1(tile, li); \
  }

  bf16v8 a[4][2], b[4][2];
  f32x4 acc[8][4];
#pragma unroll
  for (int m = 0; m < 8; ++m)
#pragma unroll
    for (int n = 0; n < 4; ++n) acc[m][n] = (f32x4){0.f, 0.f, 0.f, 0.f};

#define LDA(mh, buf)                                                        \
  {                                                                         \
    _Pragma("unroll") for (int mp = 0; mp < 4; ++mp) {                      \
      const u16* rp = (buf) + (size_t)(wm * 128 + (mh)*64 + mp * 16 + l15) * 64; \
      a[mp][0] = *(const bf16v8*)(rp + pk0 * 8);                            \
      a[mp][1] = *(const bf16v8*)(rp + (pk0 ^ 4) * 8);                      \
    }                                                                       \
  }
#define LDB(n0, buf)                                                        \
  {                                                                         \
    _Pragma("unroll") for (int nn = (n0); nn < (n0) + 2; ++nn) {            \
      const u16* rp = (buf) + (size_t)(wn * 64 + nn * 16 + l15) * 64;       \
      b[nn][0] = *(const bf16v8*)(rp + pk0 * 8);                            \
      b[nn][1] = *(const bf16v8*)(rp + (pk0 ^ 4) * 8);                      \
    }                                                                       \
  }
#define MMPH(mh, n0)                                                                      \
  {                                                                                       \
    __builtin_amdgcn_s_setprio(1);                                                        \
    _Pragma("unroll") for (int mp = 0; mp < 4; ++mp) {                                    \
      _Pragma("unroll") for (int nn = (n0); nn < (n0) + 2; ++nn) {                        \
        acc[(mh)*4 + mp][nn] = __builtin_amdgcn_mfma_f32_16x16x32_bf16(                   \
            a[mp][0], b[nn][0], acc[(mh)*4 + mp][nn], 0, 0, 0);                           \
        acc[(mh)*4 + mp][nn] = __builtin_amdgcn_mfma_f32_16x16x32_bf16(                   \
            a[mp][1], b[nn][1], acc[(mh)*4 + mp][nn], 0, 0, 0);                           \
      }                                                                                   \
    }                                                                                     \
    __builtin_amdgcn_s_setprio(0);                                                        \
  }

#pragma unroll
  for (int li = 0; li < 8; ++li) ST1(0, li);
  STG(1, 0, 5);
  __builtin_amdgcn_sched_barrier(0);
  asm volatile("s_waitcnt vmcnt(6)" ::: "memory");
  __builtin_amdgcn_s_barrier();
  LDA(0, sA);
  LDB(0, sB);

  for (int t = 0; t < NT; ++t) {
    u16* sAc = sA + (t & 1) * 16384;
    u16* sBc = sB + (t & 1) * 16384;
    u16* sAn = sA + ((t + 1) & 1) * 16384;
    u16* sBn = sB + ((t + 1) & 1) * 16384;
    STG(t + 1, 6, 7);
    MMPH(0, 0);
    LDB(2, sBc);
    __builtin_amdgcn_s_barrier();
    MMPH(0, 2);
    LDA(1, sAc);
    __builtin_amdgcn_s_barrier();
    STG(t + 2, 0, 2);
    MMPH(1, 0);
    __builtin_amdgcn_sched_barrier(0);
    if (t + 1 < NT) {
      if (t + 2 < NT) asm volatile("s_waitcnt vmcnt(3)" ::: "memory");
      else            asm volatile("s_waitcnt vmcnt(0)" ::: "memory");
    }
    __builtin_amdgcn_s_barrier();
    STG(t + 2, 3, 5);
    MMPH(1, 2);
    if (t + 1 < NT) {
      LDA(0, sAn);
      LDB(0, sBn);
    }
    __builtin_amdgcn_s_barrier();
  }

  const int lrow0 = bm + wm * 128 + l4 * 4;
  const int lcol0 = bn + wn * 64 + l15;
  const float scl = (MODE == 0 && ((bn >> 10) == 1)) ? QK_SCALE : 1.f;
  void* Cw = kh ? C1 : C0;
#pragma unroll
  for (int m = 0; m < 8; ++m) {
#pragma unroll
    for (int n = 0; n < 4; ++n) {
      const int col = lcol0 + n * 16;
      float bv = 0.f;
      if (MODE == 2) bv = bias[col];
      if (MODE == 3) bv = kh ? 0.f : bias[col];
#pragma unroll
      for (int i = 0; i < 4; ++i) {
        const int row = lrow0 + m * 16 + i;
        float v = acc[m][n][i] + bv;
        if (MODE == 2) v = fmaxf(v, 0.f);
        if (MODE == 0) v *= scl;
        if (MODE == 0 || MODE == 2)
          ((u16*)Cw)[(size_t)row * N + col] = f2b(v);
        else
          ((float*)Cw)[(size_t)row * N + col] = v;
      }
    }
  }
#undef ST1
#undef STG
#undef LDA
#undef LDB
#undef MMPH
}

// ---------------- Flash attention: 8 waves x 32 q, 32x32 MFMA, swapped ops ----------------
// S^T = mfma32(K, Q): lane owns q col (lane&31) -> softmax fully lane-local.
// O^T = mfma32(V^T from LDS, P built in-register via cvt_pk + shfl_xor(32)).
// K LDS: row-major [64][64] elems, 16B-chunk XOR swizzle (c ^= row&7), staged linearly
// via pre-swizzled global source (1 gload16/lane/tile).
// V^T LDS: R4-proven vt_write layout: kv-chunk c=kv>>3 at c*1024B, row d at
// (d ^ (d>>3))*16B, kv&7 pairs packed as u32 — writes are a full 32-bank sweep.

// MKPF: build PV B-operand frag. Required mapping (verified vs 32x32 C-layout):
//   word0 = {hi0: own A0,     hi1: partner C0}
//   word1 = {hi0: own B0,     hi1: partner D0}
//   word2 = {hi0: partner A0, hi1: own C0}
//   word3 = {hi0: partner B0, hi1: own D0}
#define MKPF(dst, A0, B0, C0, D0)                                             \
  {                                                                           \
    u32 sa = (u32)__shfl_xor((int)(A0), 32), sb = (u32)__shfl_xor((int)(B0), 32); \
    u32 sc = (u32)__shfl_xor((int)(C0), 32), sd = (u32)__shfl_xor((int)(D0), 32); \
    union { u32 u[4]; bf16v8 v; } cc;                                         \
    cc.u[0] = hi ? sc : (A0); cc.u[1] = hi ? sd : (B0);                       \
    cc.u[2] = hi ? (C0) : sa; cc.u[3] = hi ? (D0) : sb;                       \
    dst = cc.v;                                                               \
  }

// V^T staging: pair rows via shfl_xor(8) (partner tid^8 -> row vr^1), pack kv
// pairs (2t,2t+1) into u32 writes at byte (t>>2)*1024 + ((d^(d>>3))*16 + (t&3)*4.
__device__ __forceinline__ void vt_write64(u16* sVtBuf, int4 wv, int vr, int s8) {
  int4 w2;
  w2.x = __shfl_xor(wv.x, 8); w2.y = __shfl_xor(wv.y, 8);
  w2.z = __shfl_xor(wv.z, 8); w2.w = __shfl_xor(wv.w, 8);
  const int t = vr >> 1;
  const int odd = vr & 1;
  const u16* own = (const u16*)&wv;
  const u16* par = (const u16*)&w2;
  char* dstbase = (char*)sVtBuf + (t >> 2) * 1024 + (t & 3) * 4;
#pragma unroll
  for (int k = 0; k < 4; k++) {
    const unsigned lo = odd ? (unsigned)par[4 + k] : (unsigned)own[k];
    const unsigned h2 = odd ? (unsigned)own[4 + k] : (unsigned)par[k];
    const int d = s8 * 8 + k + (odd ? 4 : 0);
    const int dsw = d ^ s8;  // s8 == d>>3
    *(unsigned*)(dstbase + dsw * 16) = lo | (h2 << 16);
  }
}

__global__ __launch_bounds__(512, 4) void attn_fa(
    const u16* __restrict__ qkv, u16* __restrict__ attn) {
  __shared__ u16 sK[2][64 * 64];   // 8KB each buffer (64x64 bf16)
  __shared__ u16 sVt[2][64 * 64];  // 8KB each buffer

  const int tid = threadIdx.x, lane = tid & 63;
  const int l31 = lane & 31, hi = lane >> 5;
  const int w = ((blockIdx.x & 7) << 6) + (blockIdx.x >> 3);  // XCD swizzle (512 blocks)
  const int bh = w >> 2;
  const int b = bh >> 4, h = bh & 15;
  const int qrow0 = (w & 3) * 256 + (tid >> 6) * 32;
  const size_t rowb = (size_t)b * S_LEN * QKV_LD;
  const u16* kg = qkv + rowb + h * HD_DIM;
  const u16* qg = qkv + rowb + 1024 + h * HD_DIM;
  const u16* vg = qkv + rowb + 2048 + h * HD_DIM;
  const size_t obase = (size_t)b * (S_LEN * E_DIM) + (size_t)h * HD_DIM;

  // Q fragments (B operand): q = qrow0 + l31, k-slice ks: d = ks*16 + hi*8 + [0,8)
  bf16v8 qf[4];
#pragma unroll
  for (int ks = 0; ks < 4; ++ks)
    qf[ks] = *(const bf16v8*)(qg + (size_t)(qrow0 + l31) * QKV_LD + ks * 16 + hi * 8);

  // staging source maps (1 load per lane per tile per array)
  const int kr = tid >> 3;                     // K/V row 0..63
  const int s8 = tid & 7;                      // 8-elem chunk
  const u16* kgsrc = kg + (size_t)kr * QKV_LD + ((s8 ^ (kr & 7)) * 8);
  const u16* vgsrc = vg + (size_t)kr * QKV_LD + s8 * 8;

  f32x16 accT[2];
#pragma unroll
  for (int i = 0; i < 16; ++i) { accT[0][i] = 0.f; accT[1][i] = 0.f; }
  float mrun = -1e30f, lrun = 0.f;

  // prologue: stage tile 0
  gload16(kgsrc, sK[0] + tid * 8);
  {
    int4 v0 = *(const int4*)(vgsrc);
    vt_write64(sVt[0], v0, kr, s8);
  }
  __syncthreads();

  for (int t = 0; t < 16; ++t) {
    const int cur = t & 1;
    int4 vreg;
    if (t < 15) {
      gload16(kgsrc + (size_t)(t + 1) * 64 * QKV_LD, sK[cur ^ 1] + tid * 8);
      vreg = *(const int4*)(vgsrc + (size_t)(t + 1) * 64 * QKV_LD);
    }

    // ---- S^T = K Q^T : T0 = kv[0,32), T1 = kv[32,64); col q = l31 ----
    f32x16 T0, T1;
#pragma unroll
    for (int i = 0; i < 16; ++i) { T0[i] = 0.f; T1[i] = 0.f; }
#pragma unroll
    for (int ks = 0; ks < 4; ++ks) {
      const int ch = ((2 * ks + hi) ^ (l31 & 7)) * 8;
      const bf16v8 k0 = *(const bf16v8*)(sK[cur] + (size_t)l31 * 64 + ch);
      const bf16v8 k1 = *(const bf16v8*)(sK[cur] + (size_t)(32 + l31) * 64 + ch);
      T0 = __builtin_amdgcn_mfma_f32_32x32x16_bf16(k0, qf[ks], T0, 0, 0, 0);
      T1 = __builtin_amdgcn_mfma_f32_32x32x16_bf16(k1, qf[ks], T1, 0, 0, 0);
    }

    // ---- online softmax: lane-local (q = l31; lanes l/l+32 share q) ----
    float mx = fmaxf(T0[0], T1[0]);
#pragma unroll
    for (int r = 1; r < 16; ++r) mx = fmaxf(mx, fmaxf(T0[r], T1[r]));
    mx = fmaxf(mx, __shfl_xor(mx, 32));
    const bool skip = __all(mx <= mrun + 8.f);
    const float mnew = skip ? mrun : fmaxf(mrun, mx);
    float rs = 0.f;
#pragma unroll
    for (int r = 0; r < 16; ++r) { T0[r] = exp2f(T0[r] - mnew); rs += T0[r]; }
#pragma unroll
    for (int r = 0; r < 16; ++r) { T1[r] = exp2f(T1[r] - mnew); rs += T1[r]; }
    rs += __shfl_xor(rs, 32);
    if (skip) {
      lrun += rs;
    } else {
      const float esc = exp2f(mrun - mnew);
      mrun = mnew;
      lrun = lrun * esc + rs;
#pragma unroll
      for (int r = 0; r < 16; ++r) { accT[0][r] *= esc; accT[1][r] *= esc; }
    }

    // ---- P -> bf16 pairs: P0[wd] holds kv {2(wd&1)+8(wd>>1)+4hi, +1} ----
    u32 P0[8], P1[8];
#pragma unroll
    for (int wd = 0; wd < 8; ++wd) {
      asm("v_cvt_pk_bf16_f32 %0, %1, %2" : "=v"(P0[wd]) : "v"(T0[2 * wd]), "v"(T0[2 * wd + 1]));
      asm("v_cvt_pk_bf16_f32 %0, %1, %2" : "=v"(P1[wd]) : "v"(T1[2 * wd]), "v"(T1[2 * wd + 1]));
    }
    // B-operand frags pf[ks]: k = kv = ks*16 + hi*8 + [0,8)
    bf16v8 pf[4];
    MKPF(pf[0], P0[0], P0[1], P0[2], P0[3]);
    MKPF(pf[1], P0[4], P0[5], P0[6], P0[7]);
    MKPF(pf[2], P1[0], P1[1], P1[2], P1[3]);
    MKPF(pf[3], P1[4], P1[5], P1[6], P1[7]);

    // ---- O^T += V^T P : A-frag row d = dblk*32+l31, k = kv = ks*16+hi*8+[0,8) ----
#pragma unroll
    for (int dblk = 0; dblk < 2; ++dblk) {
      const int dd = dblk * 32 + l31;
      const int drow = (dd ^ (dd >> 3)) * 8;  // element offset within kv-chunk
#pragma unroll
      for (int ks = 0; ks < 4; ++ks) {
        const bf16v8 va = *(const bf16v8*)(sVt[cur] + (2 * ks + hi) * 512 + drow);
        accT[dblk] = __builtin_amdgcn_mfma_f32_32x32x16_bf16(va, pf[ks], accT[dblk], 0, 0, 0);
      }
    }

    if (t < 15) vt_write64(sVt[cur ^ 1], vreg, kr, s8);
    __syncthreads();
  }

  // ---- epilogue: O^T regs -> attn[q][d]; q = qrow0 + l31 ----
  const float linv = 1.f / lrun;
  u16* orow = attn + obase + (size_t)(qrow0 + l31) * E_DIM;
#pragma unroll
  for (int dblk = 0; dblk < 2; ++dblk)
#pragma unroll
    for (int a4 = 0; a4 < 4; ++a4) {
      ushort4 st;
      st.x = f2b(accT[dblk][4 * a4 + 0] * linv);
      st.y = f2b(accT[dblk][4 * a4 + 1] * linv);
      st.z = f2b(accT[dblk][4 * a4 + 2] * linv);
      st.w = f2b(accT[dblk][4 * a4 + 3] * linv);
      *(ushort4*)(orow + dblk * 32 + a4 * 8 + hi * 4) = st;
    }
}

// ---------------- LayerNorm (1 block = 1 row of 1024), ddof=1 ----------------
template<int MODE>
__global__ __launch_bounds__(256) void ln_kernel(
    const float* __restrict__ a, const float* __restrict__ b2nd, const float* __restrict__ c3rd,
    const float* __restrict__ scale, const float* __restrict__ bias,
    float* __restrict__ outf, u16* __restrict__ outb) {
  const int row = blockIdx.x;
  const int tid = threadIdx.x;
  const size_t off = (size_t)row * 1024 + tid * 4;
  float4 v = *(const float4*)(a + off);
  float4 u = *(const float4*)(b2nd + off);
  if (MODE == 0) {
    v.x = 2.f * (v.x + u.x); v.y = 2.f * (v.y + u.y);
    v.z = 2.f * (v.z + u.z); v.w = 2.f * (v.w + u.w);
  } else {
    float4 w = *(const float4*)(c3rd + off);
    v.x += u.x + w.x; v.y += u.y + w.y; v.z += u.z + w.z; v.w += u.w + w.w;
  }
  float s = v.x + v.y + v.z + v.w;
  float q = v.x * v.x + v.y * v.y + v.z * v.z + v.w * v.w;
#pragma unroll
  for (int o = 1; o < 64; o <<= 1) { s += __shfl_xor(s, o); q += __shfl_xor(q, o); }
  __shared__ float red[8];
  const int wave = tid >> 6, lane = tid & 63;
  if (lane == 0) { red[wave] = s; red[4 + wave] = q; }
  __syncthreads();
  s = red[0] + red[1] + red[2] + red[3];
  q = red[4] + red[5] + red[6] + red[7];
  const float mean = s * (1.f / 1024.f);
  const float var = (q - 1024.f * mean * mean) * (1.f / 1023.f);
  const float rstd = rsqrtf(var + 1e-5f);
  const int c = tid * 4;
  float4 sc = *(const float4*)(scale + c);
  float4 bi = *(const float4*)(bias + c);
  float4 o;
  o.x = sc.x * (v.x - mean) * rstd + bi.x;
  o.y = sc.y * (v.y - mean) * rstd + bi.y;
  o.z = sc.z * (v.z - mean) * rstd + bi.z;
  o.w = sc.w * (v.w - mean) * rstd + bi.w;
  *(float4*)(outf + off) = o;
  if (outb != nullptr) {
    ushort4 ob;
    ob.x = f2b(o.x); ob.y = f2b(o.y); ob.z = f2b(o.z); ob.w = f2b(o.w);
    *(ushort4*)(outb + off) = ob;
  }
}

// ---------------- fp32 -> bf16 cast (4 elems/thread) ----------------
__global__ __launch_bounds__(256) void cast_bf16_k(const float* __restrict__ in,
                                                   u16* __restrict__ out, int n4) {
  const int i = blockIdx.x * blockDim.x + threadIdx.x;
  if (i >= n4) return;
  float4 v = *(const float4*)(in + (size_t)i * 4);
  ushort4 o;
  o.x = f2b(v.x); o.y = f2b(v.y); o.z = f2b(v.z); o.w = f2b(v.w);
  *(ushort4*)(out + (size_t)i * 4) = o;
}

// ---------------- 1024x1024 fp32 transpose + bf16 cast ----------------
__global__ __launch_bounds__(256) void transpose_cast_k(const float* __restrict__ in,
                                                        u16* __restrict__ out) {
  __shared__ float tile[32][33];
  const int tx = threadIdx.x & 31, ty = threadIdx.x >> 5;
  const int bx = blockIdx.x * 32, by = blockIdx.y * 32;
#pragma unroll
  for (int j = 0; j < 4; j++)
    tile[ty + j * 8][tx] = in[(size_t)(by + ty + j * 8) * 1024 + bx + tx];
  __syncthreads();
#pragma unroll
  for (int j = 0; j < 4; j++)
    out[(size_t)(bx + ty + j * 8) * 1024 + by + tx] = f2b(tile[tx][ty + j * 8]);
}

extern "C" void kernel_launch(void* const* d_in, const int* in_sizes, int n_in,
                              void* d_out, int out_size, void* d_ws, size_t ws_size,
                              hipStream_t stream) {
  const float* x    = (const float*)d_in[0];
  const float* in_w = (const float*)d_in[1];
  const float* out_w = (const float*)d_in[2];
  const float* ln1s = (const float*)d_in[3];
  const float* ln1b = (const float*)d_in[4];
  const float* ln2s = (const float*)d_in[5];
  const float* ln2b = (const float*)d_in[6];
  const float* w1   = (const float*)d_in[7];
  const float* b1   = (const float*)d_in[8];
  const float* w2   = (const float*)d_in[9];
  const float* b2   = (const float*)d_in[10];
  float* outp = (float*)d_out;

  char* ws = (char*)d_ws;
  u16*   xb    = (u16*)(ws + 0);            // 16.8M; dead after QKV gemm
  u16*   qkv   = (u16*)(ws + 16777216);     // 50.3M [8192][3072]; dead after attn
  u16*   attnb = (u16*)(ws + 0);            // 16.8M over dead xb; dead after Wo
  float* attno0 = (float*)(ws + 67108864);  // 33.5M; dead after ln1
  float* attno1 = (float*)(ws + 100663296); // 33.5M; dead after ln1
  float* x1f   = (float*)(ws + 67108864);   // in-place over attno0 (row-local)
  u16*   x1b   = (u16*)(ws + 134217728);    // 16.8M; dead after FFN1
  u16*   Hb    = (u16*)(ws + 0);            // 67.1M over dead xb/qkv/attnb
  float* ffn0  = (float*)(ws + 100663296);  // over dead attno1
  u16*   wkt   = (u16*)(ws + 150994944);    // [3072][1024] concat k,q,v transposed
  u16*   wot   = wkt + 3145728;
  u16*   w1b   = wot + 1048576;
  u16*   w2b   = w1b + 4194304;
  (void)ws_size; (void)in_sizes; (void)n_in; (void)out_size;

  // casts / transposes
  cast_bf16_k<<<8192, 256, 0, stream>>>(x, xb, 2097152);
  cast_bf16_k<<<4096, 256, 0, stream>>>(w1, w1b, 1048576);
  cast_bf16_k<<<4096, 256, 0, stream>>>(w2, w2b, 1048576);
  dim3 tg(32, 32);
  transpose_cast_k<<<tg, 256, 0, stream>>>(in_w + 0,       wkt);            // k
  transpose_cast_k<<<tg, 256, 0, stream>>>(in_w + 1048576, wkt + 1048576); // q
  transpose_cast_k<<<tg, 256, 0, stream>>>(in_w + 2097152, wkt + 2097152); // v
  transpose_cast_k<<<tg, 256, 0, stream>>>(out_w,          wot);

  // fused QKV projection: [8192][3072], q block scaled by QK_SCALE
  gemm8<0><<<dim3(12, 32), 512, 0, stream>>>(xb, wkt, qkv, nullptr, nullptr, 3072, 1024, 12, 16);

  // attention: 512 blocks x 512 threads (256 q rows per block)
  attn_fa<<<512, 512, 0, stream>>>(qkv, attnb);

  // output projection, split-K=2 -> two f32 partials
  gemm8<1><<<dim3(8, 32), 512, 0, stream>>>(attnb, wot, attno0, attno1, nullptr, 1024, 1024, 4, 8);

  // ln1: x1 = LN(2*(attno0+attno1))
  ln_kernel<0><<<8192, 256, 0, stream>>>(attno0, attno1, nullptr, ln1s, ln1b, x1f, x1b);

  // FFN1: bf16 + bias + relu
  gemm8<2><<<dim3(16, 32), 512, 0, stream>>>(x1b, w1b, Hb, nullptr, b1, 4096, 1024, 16, 16);

  // FFN2: split-K=2, partial0 -> ffn0 (+bias), partial1 -> d_out scratch
  gemm8<3><<<dim3(8, 32), 512, 0, stream>>>(Hb, w2b, ffn0, outp, b2, 1024, 4096, 4, 32);

  // ln2: out = LN(x1 + ffn0 + ffn1)
  ln_kernel<1><<<8192, 256, 0, stream>>>(x1f, ffn0, outp, ln2s, ln2b, outp, nullptr);
}

// Round 7
// 368.810 us; speedup vs baseline: 1.5767x; 1.0469x over previous
//
#include <hip/hip_runtime.h>

#define E_DIM 1024
#define S_LEN 1024
#define H_NUM 16
#define HD_DIM 64
#define B_NUM 8
#define DFF_DIM 4096
#define NROWS 8192   // B*S
#define QKV_LD 3072  // fused qkv row stride

typedef unsigned short u16;
typedef unsigned u32;
typedef short bf16v8 __attribute__((ext_vector_type(8)));
typedef float f32x4 __attribute__((ext_vector_type(4)));
typedef float f32x16 __attribute__((ext_vector_type(16)));

// softmax scale folded into Q projection: 1/sqrt(64) * log2(e)
#define QK_SCALE 0.18033688011112042f

__device__ __forceinline__ u16 f2b(float f) {
  union { float f; unsigned u; } x; x.f = f;
  return (u16)((x.u + 0x7fffu + ((x.u >> 16) & 1u)) >> 16);
}

__device__ __forceinline__ void gload16(const void* g, void* l) {
  __builtin_amdgcn_global_load_lds((const __attribute__((address_space(1))) void*)g,
                                   (__attribute__((address_space(3))) void*)l, 16, 0, 0);
}

// ================= 8-phase-style GEMM, BM=BN=256, BK=64, 512 thr, 8 waves =================
// R7: full-tile prefetch — all 8 loads of tile t+2 issue at p2(t) (buffer[t&1]
// is consumed by end of p1(t)), validated by vmcnt(8) at p2(t+1): a full
// 4-phase (~600cy) latency window per load instead of 2 phases for L6-7.
template<int MODE>
__global__ __launch_bounds__(512, 2) void gemm8(
    const u16* __restrict__ A, const u16* __restrict__ Bt,
    void* __restrict__ C0, void* __restrict__ C1, const float* __restrict__ bias,
    int N, int KA, int nxt, int NT) {
  __shared__ u16 sA[2 * 16384];
  __shared__ u16 sB[2 * 16384];

  const int tid = threadIdx.x;
  const int lane = tid & 63;
  const int wid = tid >> 6;
  const int wm = wid >> 2, wn = wid & 3;
  const int l15 = lane & 15, l4 = lane >> 4;
  const int pk0 = l4 ^ (l15 & 7);

  const int gx = gridDim.x;
  const int lin = blockIdx.y * gx + blockIdx.x;
  const int chunk = (gx * gridDim.y) >> 3;
  const int swz = (lin & 7) * chunk + (lin >> 3);
  const int bym = swz / gx, bxm = swz % gx;
  const int kh = (bxm >= nxt) ? 1 : 0;
  const int bm = bym * 256;
  const int bn = (bxm - kh * nxt) * 256;
  const int k0 = kh * NT * 64;

  const int srow = tid >> 3;
  const int gch = ((tid & 7) ^ (srow & 7)) * 8;
  const u16* Ag[4];
  const u16* Bg[4];
#pragma unroll
  for (int i = 0; i < 4; ++i) {
    Ag[i] = A + k0 + (size_t)(bm + i * 64 + srow) * KA + gch;
    Bg[i] = Bt + k0 + (size_t)(bn + i * 64 + srow) * KA + gch;
  }
  const int t8 = tid * 8;

#define ST1(tile, li)                                                              \
  do {                                                                             \
    if ((li) < 4) gload16(Ag[li] + (tile) * 64, sA + ((tile)&1) * 16384 + (li)*4096 + t8); \
    else gload16(Bg[(li)-4] + (tile) * 64, sB + ((tile)&1) * 16384 + ((li)-4) * 4096 + t8); \
  } while (0)
#define STG8(tile)                                         \
  if ((tile) < NT) {                                       \
    _Pragma("unroll") for (int li = 0; li < 8; ++li) ST1(tile, li); \
  }

  bf16v8 a[4][2], b[4][2];
  f32x4 acc[8][4];
#pragma unroll
  for (int m = 0; m < 8; ++m)
#pragma unroll
    for (int n = 0; n < 4; ++n) acc[m][n] = (f32x4){0.f, 0.f, 0.f, 0.f};

#define LDA(mh, buf)                                                        \
  {                                                                         \
    _Pragma("unroll") for (int mp = 0; mp < 4; ++mp) {                      \
      const u16* rp = (buf) + (size_t)(wm * 128 + (mh)*64 + mp * 16 + l15) * 64; \
      a[mp][0] = *(const bf16v8*)(rp + pk0 * 8);                            \
      a[mp][1] = *(const bf16v8*)(rp + (pk0 ^ 4) * 8);                      \
    }                                                                       \
  }
#define LDB(n0, buf)                                                        \
  {                                                                         \
    _Pragma("unroll") for (int nn = (n0); nn < (n0) + 2; ++nn) {            \
      const u16* rp = (buf) + (size_t)(wn * 64 + nn * 16 + l15) * 64;       \
      b[nn][0] = *(const bf16v8*)(rp + pk0 * 8);                            \
      b[nn][1] = *(const bf16v8*)(rp + (pk0 ^ 4) * 8);                      \
    }                                                                       \
  }
#define MMPH(mh, n0)                                                                      \
  {                                                                                       \
    __builtin_amdgcn_s_setprio(1);                                                        \
    _Pragma("unroll") for (int mp = 0; mp < 4; ++mp) {                                    \
      _Pragma("unroll") for (int nn = (n0); nn < (n0) + 2; ++nn) {                        \
        acc[(mh)*4 + mp][nn] = __builtin_amdgcn_mfma_f32_16x16x32_bf16(                   \
            a[mp][0], b[nn][0], acc[(mh)*4 + mp][nn], 0, 0, 0);                           \
        acc[(mh)*4 + mp][nn] = __builtin_amdgcn_mfma_f32_16x16x32_bf16(                   \
            a[mp][1], b[nn][1], acc[(mh)*4 + mp][nn], 0, 0, 0);                           \
      }                                                                                   \
    }                                                                                     \
    __builtin_amdgcn_s_setprio(0);                                                        \
  }

  // ---- prologue: tiles 0 and 1 fully staged; validate tile 0; pre-read frags ----
  STG8(0);
  STG8(1);
  __builtin_amdgcn_sched_barrier(0);
  asm volatile("s_waitcnt vmcnt(8)" ::: "memory");
  __builtin_amdgcn_s_barrier();
  LDA(0, sA);
  LDB(0, sB);

  for (int t = 0; t < NT; ++t) {
    u16* sAc = sA + (t & 1) * 16384;
    u16* sBc = sB + (t & 1) * 16384;
    u16* sAn = sA + ((t + 1) & 1) * 16384;
    u16* sBn = sB + ((t + 1) & 1) * 16384;
    // ---- p0 ----
    MMPH(0, 0);
    LDB(2, sBc);
    __builtin_amdgcn_s_barrier();
    // ---- p1 ---- (tile t buffer fully consumed after this phase)
    MMPH(0, 2);
    LDA(1, sAc);
    __builtin_amdgcn_s_barrier();
    // ---- p2: issue ALL of tile t+2 into buffer[t&1]; validate tile t+1 ----
    STG8(t + 2);
    MMPH(1, 0);
    __builtin_amdgcn_sched_barrier(0);
    if (t + 2 < NT)      asm volatile("s_waitcnt vmcnt(8)" ::: "memory");
    else if (t + 1 < NT) asm volatile("s_waitcnt vmcnt(0)" ::: "memory");
    __builtin_amdgcn_s_barrier();
    // ---- p3 ----
    MMPH(1, 2);
    if (t + 1 < NT) {
      LDA(0, sAn);
      LDB(0, sBn);
    }
    __builtin_amdgcn_s_barrier();
  }

  // ---- epilogue ----
  const int lrow0 = bm + wm * 128 + l4 * 4;
  const int lcol0 = bn + wn * 64 + l15;
  const float scl = (MODE == 0 && ((bn >> 10) == 1)) ? QK_SCALE : 1.f;
  void* Cw = kh ? C1 : C0;
#pragma unroll
  for (int m = 0; m < 8; ++m) {
#pragma unroll
    for (int n = 0; n < 4; ++n) {
      const int col = lcol0 + n * 16;
      float bv = 0.f;
      if (MODE == 2) bv = bias[col];
      if (MODE == 3) bv = kh ? 0.f : bias[col];
#pragma unroll
      for (int i = 0; i < 4; ++i) {
        const int row = lrow0 + m * 16 + i;
        float v = acc[m][n][i] + bv;
        if (MODE == 2) v = fmaxf(v, 0.f);
        if (MODE == 0) v *= scl;
        if (MODE == 0 || MODE == 2)
          ((u16*)Cw)[(size_t)row * N + col] = f2b(v);
        else
          ((float*)Cw)[(size_t)row * N + col] = v;
      }
    }
  }
#undef ST1
#undef STG8
#undef LDA
#undef LDB
#undef MMPH
}

// ---------------- Flash attention: 8 waves x 32 q, 32x32 MFMA, swapped ops ----------------
// (unchanged from R6 — verified)
#define MKPF(dst, A0, B0, C0, D0)                                             \
  {                                                                           \
    u32 sa = (u32)__shfl_xor((int)(A0), 32), sb = (u32)__shfl_xor((int)(B0), 32); \
    u32 sc = (u32)__shfl_xor((int)(C0), 32), sd = (u32)__shfl_xor((int)(D0), 32); \
    union { u32 u[4]; bf16v8 v; } cc;                                         \
    cc.u[0] = hi ? sc : (A0); cc.u[1] = hi ? sd : (B0);                       \
    cc.u[2] = hi ? (C0) : sa; cc.u[3] = hi ? (D0) : sb;                       \
    dst = cc.v;                                                               \
  }

__device__ __forceinline__ void vt_write64(u16* sVtBuf, int4 wv, int vr, int s8) {
  int4 w2;
  w2.x = __shfl_xor(wv.x, 8); w2.y = __shfl_xor(wv.y, 8);
  w2.z = __shfl_xor(wv.z, 8); w2.w = __shfl_xor(wv.w, 8);
  const int t = vr >> 1;
  const int odd = vr & 1;
  const u16* own = (const u16*)&wv;
  const u16* par = (const u16*)&w2;
  char* dstbase = (char*)sVtBuf + (t >> 2) * 1024 + (t & 3) * 4;
#pragma unroll
  for (int k = 0; k < 4; k++) {
    const unsigned lo = odd ? (unsigned)par[4 + k] : (unsigned)own[k];
    const unsigned h2 = odd ? (unsigned)own[4 + k] : (unsigned)par[k];
    const int d = s8 * 8 + k + (odd ? 4 : 0);
    const int dsw = d ^ s8;  // s8 == d>>3
    *(unsigned*)(dstbase + dsw * 16) = lo | (h2 << 16);
  }
}

__global__ __launch_bounds__(512, 4) void attn_fa(
    const u16* __restrict__ qkv, u16* __restrict__ attn) {
  __shared__ u16 sK[2][64 * 64];
  __shared__ u16 sVt[2][64 * 64];

  const int tid = threadIdx.x, lane = tid & 63;
  const int l31 = lane & 31, hi = lane >> 5;
  const int w = ((blockIdx.x & 7) << 6) + (blockIdx.x >> 3);  // XCD swizzle (512 blocks)
  const int bh = w >> 2;
  const int b = bh >> 4, h = bh & 15;
  const int qrow0 = (w & 3) * 256 + (tid >> 6) * 32;
  const size_t rowb = (size_t)b * S_LEN * QKV_LD;
  const u16* kg = qkv + rowb + h * HD_DIM;
  const u16* qg = qkv + rowb + 1024 + h * HD_DIM;
  const u16* vg = qkv + rowb + 2048 + h * HD_DIM;
  const size_t obase = (size_t)b * (S_LEN * E_DIM) + (size_t)h * HD_DIM;

  bf16v8 qf[4];
#pragma unroll
  for (int ks = 0; ks < 4; ++ks)
    qf[ks] = *(const bf16v8*)(qg + (size_t)(qrow0 + l31) * QKV_LD + ks * 16 + hi * 8);

  const int kr = tid >> 3;
  const int s8 = tid & 7;
  const u16* kgsrc = kg + (size_t)kr * QKV_LD + ((s8 ^ (kr & 7)) * 8);
  const u16* vgsrc = vg + (size_t)kr * QKV_LD + s8 * 8;

  f32x16 accT[2];
#pragma unroll
  for (int i = 0; i < 16; ++i) { accT[0][i] = 0.f; accT[1][i] = 0.f; }
  float mrun = -1e30f, lrun = 0.f;

  gload16(kgsrc, sK[0] + tid * 8);
  {
    int4 v0 = *(const int4*)(vgsrc);
    vt_write64(sVt[0], v0, kr, s8);
  }
  __syncthreads();

  for (int t = 0; t < 16; ++t) {
    const int cur = t & 1;
    int4 vreg;
    if (t < 15) {
      gload16(kgsrc + (size_t)(t + 1) * 64 * QKV_LD, sK[cur ^ 1] + tid * 8);
      vreg = *(const int4*)(vgsrc + (size_t)(t + 1) * 64 * QKV_LD);
    }

    f32x16 T0, T1;
#pragma unroll
    for (int i = 0; i < 16; ++i) { T0[i] = 0.f; T1[i] = 0.f; }
#pragma unroll
    for (int ks = 0; ks < 4; ++ks) {
      const int ch = ((2 * ks + hi) ^ (l31 & 7)) * 8;
      const bf16v8 k0 = *(const bf16v8*)(sK[cur] + (size_t)l31 * 64 + ch);
      const bf16v8 k1 = *(const bf16v8*)(sK[cur] + (size_t)(32 + l31) * 64 + ch);
      T0 = __builtin_amdgcn_mfma_f32_32x32x16_bf16(k0, qf[ks], T0, 0, 0, 0);
      T1 = __builtin_amdgcn_mfma_f32_32x32x16_bf16(k1, qf[ks], T1, 0, 0, 0);
    }

    float mx = fmaxf(T0[0], T1[0]);
#pragma unroll
    for (int r = 1; r < 16; ++r) mx = fmaxf(mx, fmaxf(T0[r], T1[r]));
    mx = fmaxf(mx, __shfl_xor(mx, 32));
    const bool skip = __all(mx <= mrun + 8.f);
    const float mnew = skip ? mrun : fmaxf(mrun, mx);
    float rs = 0.f;
#pragma unroll
    for (int r = 0; r < 16; ++r) { T0[r] = exp2f(T0[r] - mnew); rs += T0[r]; }
#pragma unroll
    for (int r = 0; r < 16; ++r) { T1[r] = exp2f(T1[r] - mnew); rs += T1[r]; }
    rs += __shfl_xor(rs, 32);
    if (skip) {
      lrun += rs;
    } else {
      const float esc = exp2f(mrun - mnew);
      mrun = mnew;
      lrun = lrun * esc + rs;
#pragma unroll
      for (int r = 0; r < 16; ++r) { accT[0][r] *= esc; accT[1][r] *= esc; }
    }

    u32 P0[8], P1[8];
#pragma unroll
    for (int wd = 0; wd < 8; ++wd) {
      asm("v_cvt_pk_bf16_f32 %0, %1, %2" : "=v"(P0[wd]) : "v"(T0[2 * wd]), "v"(T0[2 * wd + 1]));
      asm("v_cvt_pk_bf16_f32 %0, %1, %2" : "=v"(P1[wd]) : "v"(T1[2 * wd]), "v"(T1[2 * wd + 1]));
    }
    bf16v8 pf[4];
    MKPF(pf[0], P0[0], P0[1], P0[2], P0[3]);
    MKPF(pf[1], P0[4], P0[5], P0[6], P0[7]);
    MKPF(pf[2], P1[0], P1[1], P1[2], P1[3]);
    MKPF(pf[3], P1[4], P1[5], P1[6], P1[7]);

#pragma unroll
    for (int dblk = 0; dblk < 2; ++dblk) {
      const int dd = dblk * 32 + l31;
      const int drow = (dd ^ (dd >> 3)) * 8;
#pragma unroll
      for (int ks = 0; ks < 4; ++ks) {
        const bf16v8 va = *(const bf16v8*)(sVt[cur] + (2 * ks + hi) * 512 + drow);
        accT[dblk] = __builtin_amdgcn_mfma_f32_32x32x16_bf16(va, pf[ks], accT[dblk], 0, 0, 0);
      }
    }

    if (t < 15) vt_write64(sVt[cur ^ 1], vreg, kr, s8);
    __syncthreads();
  }

  const float linv = 1.f / lrun;
  u16* orow = attn + obase + (size_t)(qrow0 + l31) * E_DIM;
#pragma unroll
  for (int dblk = 0; dblk < 2; ++dblk)
#pragma unroll
    for (int a4 = 0; a4 < 4; ++a4) {
      ushort4 st;
      st.x = f2b(accT[dblk][4 * a4 + 0] * linv);
      st.y = f2b(accT[dblk][4 * a4 + 1] * linv);
      st.z = f2b(accT[dblk][4 * a4 + 2] * linv);
      st.w = f2b(accT[dblk][4 * a4 + 3] * linv);
      *(ushort4*)(orow + dblk * 32 + a4 * 8 + hi * 4) = st;
    }
}

// ---------------- LayerNorm (1 block = 1 row of 1024), ddof=1 ----------------
template<int MODE>
__global__ __launch_bounds__(256) void ln_kernel(
    const float* __restrict__ a, const float* __restrict__ b2nd, const float* __restrict__ c3rd,
    const float* __restrict__ scale, const float* __restrict__ bias,
    float* __restrict__ outf, u16* __restrict__ outb) {
  const int row = blockIdx.x;
  const int tid = threadIdx.x;
  const size_t off = (size_t)row * 1024 + tid * 4;
  float4 v = *(const float4*)(a + off);
  float4 u = *(const float4*)(b2nd + off);
  if (MODE == 0) {
    v.x = 2.f * (v.x + u.x); v.y = 2.f * (v.y + u.y);
    v.z = 2.f * (v.z + u.z); v.w = 2.f * (v.w + u.w);
  } else {
    float4 w = *(const float4*)(c3rd + off);
    v.x += u.x + w.x; v.y += u.y + w.y; v.z += u.z + w.z; v.w += u.w + w.w;
  }
  float s = v.x + v.y + v.z + v.w;
  float q = v.x * v.x + v.y * v.y + v.z * v.z + v.w * v.w;
#pragma unroll
  for (int o = 1; o < 64; o <<= 1) { s += __shfl_xor(s, o); q += __shfl_xor(q, o); }
  __shared__ float red[8];
  const int wave = tid >> 6, lane = tid & 63;
  if (lane == 0) { red[wave] = s; red[4 + wave] = q; }
  __syncthreads();
  s = red[0] + red[1] + red[2] + red[3];
  q = red[4] + red[5] + red[6] + red[7];
  const float mean = s * (1.f / 1024.f);
  const float var = (q - 1024.f * mean * mean) * (1.f / 1023.f);
  const float rstd = rsqrtf(var + 1e-5f);
  const int c = tid * 4;
  float4 sc = *(const float4*)(scale + c);
  float4 bi = *(const float4*)(bias + c);
  float4 o;
  o.x = sc.x * (v.x - mean) * rstd + bi.x;
  o.y = sc.y * (v.y - mean) * rstd + bi.y;
  o.z = sc.z * (v.z - mean) * rstd + bi.z;
  o.w = sc.w * (v.w - mean) * rstd + bi.w;
  *(float4*)(outf + off) = o;
  if (outb != nullptr) {
    ushort4 ob;
    ob.x = f2b(o.x); ob.y = f2b(o.y); ob.z = f2b(o.z); ob.w = f2b(o.w);
    *(ushort4*)(outb + off) = ob;
  }
}

// ---------------- fp32 -> bf16 cast (4 elems/thread) ----------------
__global__ __launch_bounds__(256) void cast_bf16_k(const float* __restrict__ in,
                                                   u16* __restrict__ out, int n4) {
  const int i = blockIdx.x * blockDim.x + threadIdx.x;
  if (i >= n4) return;
  float4 v = *(const float4*)(in + (size_t)i * 4);
  ushort4 o;
  o.x = f2b(v.x); o.y = f2b(v.y); o.z = f2b(v.z); o.w = f2b(v.w);
  *(ushort4*)(out + (size_t)i * 4) = o;
}

// ---------------- 1024x1024 fp32 transpose + bf16 cast ----------------
__global__ __launch_bounds__(256) void transpose_cast_k(const float* __restrict__ in,
                                                        u16* __restrict__ out) {
  __shared__ float tile[32][33];
  const int tx = threadIdx.x & 31, ty = threadIdx.x >> 5;
  const int bx = blockIdx.x * 32, by = blockIdx.y * 32;
#pragma unroll
  for (int j = 0; j < 4; j++)
    tile[ty + j * 8][tx] = in[(size_t)(by + ty + j * 8) * 1024 + bx + tx];
  __syncthreads();
#pragma unroll
  for (int j = 0; j < 4; j++)
    out[(size_t)(bx + ty + j * 8) * 1024 + by + tx] = f2b(tile[tx][ty + j * 8]);
}

extern "C" void kernel_launch(void* const* d_in, const int* in_sizes, int n_in,
                              void* d_out, int out_size, void* d_ws, size_t ws_size,
                              hipStream_t stream) {
  const float* x    = (const float*)d_in[0];
  const float* in_w = (const float*)d_in[1];
  const float* out_w = (const float*)d_in[2];
  const float* ln1s = (const float*)d_in[3];
  const float* ln1b = (const float*)d_in[4];
  const float* ln2s = (const float*)d_in[5];
  const float* ln2b = (const float*)d_in[6];
  const float* w1   = (const float*)d_in[7];
  const float* b1   = (const float*)d_in[8];
  const float* w2   = (const float*)d_in[9];
  const float* b2   = (const float*)d_in[10];
  float* outp = (float*)d_out;

  char* ws = (char*)d_ws;
  u16*   xb    = (u16*)(ws + 0);            // 16.8M; dead after QKV gemm
  u16*   qkv   = (u16*)(ws + 16777216);     // 50.3M [8192][3072]; dead after attn
  u16*   attnb = (u16*)(ws + 0);            // 16.8M over dead xb; dead after Wo
  float* attno0 = (float*)(ws + 67108864);  // 33.5M; dead after ln1
  float* attno1 = (float*)(ws + 100663296); // 33.5M; dead after ln1
  float* x1f   = (float*)(ws + 67108864);   // in-place over attno0 (row-local)
  u16*   x1b   = (u16*)(ws + 134217728);    // 16.8M; dead after FFN1
  u16*   Hb    = (u16*)(ws + 0);            // 67.1M over dead xb/qkv/attnb
  float* ffn0  = (float*)(ws + 100663296);  // over dead attno1
  u16*   wkt   = (u16*)(ws + 150994944);    // [3072][1024] concat k,q,v transposed
  u16*   wot   = wkt + 3145728;
  u16*   w1b   = wot + 1048576;
  u16*   w2b   = w1b + 4194304;
  (void)ws_size; (void)in_sizes; (void)n_in; (void)out_size;

  // casts / transposes
  cast_bf16_k<<<8192, 256, 0, stream>>>(x, xb, 2097152);
  cast_bf16_k<<<4096, 256, 0, stream>>>(w1, w1b, 1048576);
  cast_bf16_k<<<4096, 256, 0, stream>>>(w2, w2b, 1048576);
  dim3 tg(32, 32);
  transpose_cast_k<<<tg, 256, 0, stream>>>(in_w + 0,       wkt);            // k
  transpose_cast_k<<<tg, 256, 0, stream>>>(in_w + 1048576, wkt + 1048576); // q
  transpose_cast_k<<<tg, 256, 0, stream>>>(in_w + 2097152, wkt + 2097152); // v
  transpose_cast_k<<<tg, 256, 0, stream>>>(out_w,          wot);

  // fused QKV projection: [8192][3072], q block scaled by QK_SCALE
  gemm8<0><<<dim3(12, 32), 512, 0, stream>>>(xb, wkt, qkv, nullptr, nullptr, 3072, 1024, 12, 16);

  // attention: 512 blocks x 512 threads (256 q rows per block)
  attn_fa<<<512, 512, 0, stream>>>(qkv, attnb);

  // output projection, split-K=2 -> two f32 partials
  gemm8<1><<<dim3(8, 32), 512, 0, stream>>>(attnb, wot, attno0, attno1, nullptr, 1024, 1024, 4, 8);

  // ln1: x1 = LN(2*(attno0+attno1))
  ln_kernel<0><<<8192, 256, 0, stream>>>(attno0, attno1, nullptr, ln1s, ln1b, x1f, x1b);

  // FFN1: bf16 + bias + relu
  gemm8<2><<<dim3(16, 32), 512, 0, stream>>>(x1b, w1b, Hb, nullptr, b1, 4096, 1024, 16, 16);

  // FFN2: split-K=2, partial0 -> ffn0 (+bias), partial1 -> d_out scratch
  gemm8<3><<<dim3(8, 32), 512, 0, stream>>>(Hb, w2b, ffn0, outp, b2, 1024, 4096, 4, 32);

  // ln2: out = LN(x1 + ffn0 + ffn1)
  ln_kernel<1><<<8192, 256, 0, stream>>>(x1f, ffn0, outp, ln2s, ln2b, outp, nullptr);
}

// Round 9
// 346.915 us; speedup vs baseline: 1.6762x; 1.0631x over previous
//
#include <hip/hip_runtime.h>

#define E_DIM 1024
#define S_LEN 1024
#define H_NUM 16
#define HD_DIM 64
#define B_NUM 8
#define DFF_DIM 4096
#define NROWS 8192   // B*S
#define QKV_LD 3072  // fused qkv row stride

typedef unsigned short u16;
typedef unsigned u32;
typedef short bf16v8 __attribute__((ext_vector_type(8)));
typedef float f32x4 __attribute__((ext_vector_type(4)));
typedef float f32x16 __attribute__((ext_vector_type(16)));

// softmax scale folded into Q projection: 1/sqrt(64) * log2(e)
#define QK_SCALE 0.18033688011112042f

__device__ __forceinline__ u16 f2b(float f) {
  union { float f; unsigned u; } x; x.f = f;
  return (u16)((x.u + 0x7fffu + ((x.u >> 16) & 1u)) >> 16);
}

__device__ __forceinline__ float b2f(u16 v) {
  union { unsigned u; float f; } x; x.u = ((unsigned)v) << 16; return x.f;
}

__device__ __forceinline__ float max3f(float a, float b, float c) {
  return fmaxf(fmaxf(a, b), c);  // clang fuses to v_max3_f32
}

__device__ __forceinline__ void gload16(const void* g, void* l) {
  __builtin_amdgcn_global_load_lds((const __attribute__((address_space(1))) void*)g,
                                   (__attribute__((address_space(3))) void*)l, 16, 0, 0);
}

// ================= 8-phase-style GEMM, BM=BN=256, BK=64, 512 thr, 8 waves =================
// R7-verified schedule (full-tile prefetch, counted vmcnt(8)).
// R9: ALL modes write bf16 outputs (split-K partials in bf16 — traffic cut).
// MODE 0: bf16 out, cols [1024,2048) scaled by QK_SCALE (fused QKV).
// MODE 1: bf16 partial out (split-K: kh ? C1 : C0), no bias.        (Wo)
// MODE 2: bf16 out + bias + relu.                                    (FFN1)
// MODE 3: bf16 partial out + bias only on kh==0.                     (FFN2)
template<int MODE>
__global__ __launch_bounds__(512, 2) void gemm8(
    const u16* __restrict__ A, const u16* __restrict__ Bt,
    void* __restrict__ C0, void* __restrict__ C1, const float* __restrict__ bias,
    int N, int KA, int nxt, int NT) {
  __shared__ u16 sA[2 * 16384];
  __shared__ u16 sB[2 * 16384];

  const int tid = threadIdx.x;
  const int lane = tid & 63;
  const int wid = tid >> 6;
  const int wm = wid >> 2, wn = wid & 3;
  const int l15 = lane & 15, l4 = lane >> 4;
  const int pk0 = l4 ^ (l15 & 7);

  const int gx = gridDim.x;
  const int lin = blockIdx.y * gx + blockIdx.x;
  const int chunk = (gx * gridDim.y) >> 3;
  const int swz = (lin & 7) * chunk + (lin >> 3);
  const int bym = swz / gx, bxm = swz % gx;
  const int kh = (bxm >= nxt) ? 1 : 0;
  const int bm = bym * 256;
  const int bn = (bxm - kh * nxt) * 256;
  const int k0 = kh * NT * 64;

  const int srow = tid >> 3;
  const int gch = ((tid & 7) ^ (srow & 7)) * 8;
  const u16* Ag[4];
  const u16* Bg[4];
#pragma unroll
  for (int i = 0; i < 4; ++i) {
    Ag[i] = A + k0 + (size_t)(bm + i * 64 + srow) * KA + gch;
    Bg[i] = Bt + k0 + (size_t)(bn + i * 64 + srow) * KA + gch;
  }
  const int t8 = tid * 8;

#define ST1(tile, li)                                                              \
  do {                                                                             \
    if ((li) < 4) gload16(Ag[li] + (tile) * 64, sA + ((tile)&1) * 16384 + (li)*4096 + t8); \
    else gload16(Bg[(li)-4] + (tile) * 64, sB + ((tile)&1) * 16384 + ((li)-4) * 4096 + t8); \
  } while (0)
#define STG8(tile)                                         \
  if ((tile) < NT) {                                       \
    _Pragma("unroll") for (int li = 0; li < 8; ++li) ST1(tile, li); \
  }

  bf16v8 a[4][2], b[4][2];
  f32x4 acc[8][4];
#pragma unroll
  for (int m = 0; m < 8; ++m)
#pragma unroll
    for (int n = 0; n < 4; ++n) acc[m][n] = (f32x4){0.f, 0.f, 0.f, 0.f};

#define LDA(mh, buf)                                                        \
  {                                                                         \
    _Pragma("unroll") for (int mp = 0; mp < 4; ++mp) {                      \
      const u16* rp = (buf) + (size_t)(wm * 128 + (mh)*64 + mp * 16 + l15) * 64; \
      a[mp][0] = *(const bf16v8*)(rp + pk0 * 8);                            \
      a[mp][1] = *(const bf16v8*)(rp + (pk0 ^ 4) * 8);                      \
    }                                                                       \
  }
#define LDB(n0, buf)                                                        \
  {                                                                         \
    _Pragma("unroll") for (int nn = (n0); nn < (n0) + 2; ++nn) {            \
      const u16* rp = (buf) + (size_t)(wn * 64 + nn * 16 + l15) * 64;       \
      b[nn][0] = *(const bf16v8*)(rp + pk0 * 8);                            \
      b[nn][1] = *(const bf16v8*)(rp + (pk0 ^ 4) * 8);                      \
    }                                                                       \
  }
#define MMPH(mh, n0)                                                                      \
  {                                                                                       \
    __builtin_amdgcn_s_setprio(1);                                                        \
    _Pragma("unroll") for (int mp = 0; mp < 4; ++mp) {                                    \
      _Pragma("unroll") for (int nn = (n0); nn < (n0) + 2; ++nn) {                        \
        acc[(mh)*4 + mp][nn] = __builtin_amdgcn_mfma_f32_16x16x32_bf16(                   \
            a[mp][0], b[nn][0], acc[(mh)*4 + mp][nn], 0, 0, 0);                           \
        acc[(mh)*4 + mp][nn] = __builtin_amdgcn_mfma_f32_16x16x32_bf16(                   \
            a[mp][1], b[nn][1], acc[(mh)*4 + mp][nn], 0, 0, 0);                           \
      }                                                                                   \
    }                                                                                     \
    __builtin_amdgcn_s_setprio(0);                                                        \
  }

  // ---- prologue: tiles 0 and 1 fully staged; validate tile 0; pre-read frags ----
  STG8(0);
  STG8(1);
  __builtin_amdgcn_sched_barrier(0);
  asm volatile("s_waitcnt vmcnt(8)" ::: "memory");
  __builtin_amdgcn_s_barrier();
  LDA(0, sA);
  LDB(0, sB);

  for (int t = 0; t < NT; ++t) {
    u16* sAc = sA + (t & 1) * 16384;
    u16* sBc = sB + (t & 1) * 16384;
    u16* sAn = sA + ((t + 1) & 1) * 16384;
    u16* sBn = sB + ((t + 1) & 1) * 16384;
    // ---- p0 ----
    MMPH(0, 0);
    LDB(2, sBc);
    __builtin_amdgcn_s_barrier();
    // ---- p1 ---- (tile t buffer fully consumed after this phase)
    MMPH(0, 2);
    LDA(1, sAc);
    __builtin_amdgcn_s_barrier();
    // ---- p2: issue ALL of tile t+2 into buffer[t&1]; validate tile t+1 ----
    STG8(t + 2);
    MMPH(1, 0);
    __builtin_amdgcn_sched_barrier(0);
    if (t + 2 < NT)      asm volatile("s_waitcnt vmcnt(8)" ::: "memory");
    else if (t + 1 < NT) asm volatile("s_waitcnt vmcnt(0)" ::: "memory");
    __builtin_amdgcn_s_barrier();
    // ---- p3 ----
    MMPH(1, 2);
    if (t + 1 < NT) {
      LDA(0, sAn);
      LDB(0, sBn);
    }
    __builtin_amdgcn_s_barrier();
  }

  // ---- epilogue (all modes: bf16 out) ----
  const int lrow0 = bm + wm * 128 + l4 * 4;
  const int lcol0 = bn + wn * 64 + l15;
  const float scl = (MODE == 0 && ((bn >> 10) == 1)) ? QK_SCALE : 1.f;
  u16* Cw = (u16*)(kh ? C1 : C0);
#pragma unroll
  for (int m = 0; m < 8; ++m) {
#pragma unroll
    for (int n = 0; n < 4; ++n) {
      const int col = lcol0 + n * 16;
      float bv = 0.f;
      if (MODE == 2) bv = bias[col];
      if (MODE == 3) bv = kh ? 0.f : bias[col];
#pragma unroll
      for (int i = 0; i < 4; ++i) {
        const int row = lrow0 + m * 16 + i;
        float v = acc[m][n][i] + bv;
        if (MODE == 2) v = fmaxf(v, 0.f);
        if (MODE == 0) v *= scl;
        Cw[(size_t)row * N + col] = f2b(v);
      }
    }
  }
#undef ST1
#undef STG8
#undef LDA
#undef LDB
#undef MMPH
}

// ---------------- Flash attention: 8 waves x 32 q, 32x32 MFMA, swapped ops ----------------
// R7-verified structure. R9 edits (in-lane only): max3 tree; lane-local lrun
// with single cross-half merge in epilogue. MKPF = R6/R7-verified shfl form.
#define MKPF(dst, A0, B0, C0, D0)                                             \
  {                                                                           \
    u32 sa = (u32)__shfl_xor((int)(A0), 32), sb = (u32)__shfl_xor((int)(B0), 32); \
    u32 sc = (u32)__shfl_xor((int)(C0), 32), sd = (u32)__shfl_xor((int)(D0), 32); \
    union { u32 u[4]; bf16v8 v; } cc;                                         \
    cc.u[0] = hi ? sc : (A0); cc.u[1] = hi ? sd : (B0);                       \
    cc.u[2] = hi ? (C0) : sa; cc.u[3] = hi ? (D0) : sb;                       \
    dst = cc.v;                                                               \
  }

__device__ __forceinline__ void vt_write64(u16* sVtBuf, int4 wv, int vr, int s8) {
  int4 w2;
  w2.x = __shfl_xor(wv.x, 8); w2.y = __shfl_xor(wv.y, 8);
  w2.z = __shfl_xor(wv.z, 8); w2.w = __shfl_xor(wv.w, 8);
  const int t = vr >> 1;
  const int odd = vr & 1;
  const u16* own = (const u16*)&wv;
  const u16* par = (const u16*)&w2;
  char* dstbase = (char*)sVtBuf + (t >> 2) * 1024 + (t & 3) * 4;
#pragma unroll
  for (int k = 0; k < 4; k++) {
    const unsigned lo = odd ? (unsigned)par[4 + k] : (unsigned)own[k];
    const unsigned h2 = odd ? (unsigned)own[4 + k] : (unsigned)par[k];
    const int d = s8 * 8 + k + (odd ? 4 : 0);
    const int dsw = d ^ s8;  // s8 == d>>3
    *(unsigned*)(dstbase + dsw * 16) = lo | (h2 << 16);
  }
}

__global__ __launch_bounds__(512, 4) void attn_fa(
    const u16* __restrict__ qkv, u16* __restrict__ attn) {
  __shared__ u16 sK[2][64 * 64];
  __shared__ u16 sVt[2][64 * 64];

  const int tid = threadIdx.x, lane = tid & 63;
  const int l31 = lane & 31, hi = lane >> 5;
  const int w = ((blockIdx.x & 7) << 6) + (blockIdx.x >> 3);  // XCD swizzle (512 blocks)
  const int bh = w >> 2;
  const int b = bh >> 4, h = bh & 15;
  const int qrow0 = (w & 3) * 256 + (tid >> 6) * 32;
  const size_t rowb = (size_t)b * S_LEN * QKV_LD;
  const u16* kg = qkv + rowb + h * HD_DIM;
  const u16* qg = qkv + rowb + 1024 + h * HD_DIM;
  const u16* vg = qkv + rowb + 2048 + h * HD_DIM;
  const size_t obase = (size_t)b * (S_LEN * E_DIM) + (size_t)h * HD_DIM;

  bf16v8 qf[4];
#pragma unroll
  for (int ks = 0; ks < 4; ++ks)
    qf[ks] = *(const bf16v8*)(qg + (size_t)(qrow0 + l31) * QKV_LD + ks * 16 + hi * 8);

  const int kr = tid >> 3;
  const int s8 = tid & 7;
  const u16* kgsrc = kg + (size_t)kr * QKV_LD + ((s8 ^ (kr & 7)) * 8);
  const u16* vgsrc = vg + (size_t)kr * QKV_LD + s8 * 8;

  f32x16 accT[2];
#pragma unroll
  for (int i = 0; i < 16; ++i) { accT[0][i] = 0.f; accT[1][i] = 0.f; }
  float mrun = -1e30f, lrun = 0.f;

  gload16(kgsrc, sK[0] + tid * 8);
  {
    int4 v0 = *(const int4*)(vgsrc);
    vt_write64(sVt[0], v0, kr, s8);
  }
  __syncthreads();

  for (int t = 0; t < 16; ++t) {
    const int cur = t & 1;
    int4 vreg;
    if (t < 15) {
      gload16(kgsrc + (size_t)(t + 1) * 64 * QKV_LD, sK[cur ^ 1] + tid * 8);
      vreg = *(const int4*)(vgsrc + (size_t)(t + 1) * 64 * QKV_LD);
    }

    f32x16 T0, T1;
#pragma unroll
    for (int i = 0; i < 16; ++i) { T0[i] = 0.f; T1[i] = 0.f; }
#pragma unroll
    for (int ks = 0; ks < 4; ++ks) {
      const int ch = ((2 * ks + hi) ^ (l31 & 7)) * 8;
      const bf16v8 k0 = *(const bf16v8*)(sK[cur] + (size_t)l31 * 64 + ch);
      const bf16v8 k1 = *(const bf16v8*)(sK[cur] + (size_t)(32 + l31) * 64 + ch);
      T0 = __builtin_amdgcn_mfma_f32_32x32x16_bf16(k0, qf[ks], T0, 0, 0, 0);
      T1 = __builtin_amdgcn_mfma_f32_32x32x16_bf16(k1, qf[ks], T1, 0, 0, 0);
    }

    // ---- online softmax: max3 tree + single cross-half shfl ----
    float ma = fmaxf(T0[0], T0[1]);
#pragma unroll
    for (int r = 2; r < 16; r += 2) ma = max3f(ma, T0[r], T0[r + 1]);
    float mb = fmaxf(T1[0], T1[1]);
#pragma unroll
    for (int r = 2; r < 16; r += 2) mb = max3f(mb, T1[r], T1[r + 1]);
    float mx = fmaxf(ma, mb);
    mx = fmaxf(mx, __shfl_xor(mx, 32));
    const bool skip = __all(mx <= mrun + 8.f);
    const float mnew = skip ? mrun : fmaxf(mrun, mx);
    float rs = 0.f;
#pragma unroll
    for (int r = 0; r < 16; ++r) { T0[r] = exp2f(T0[r] - mnew); rs += T0[r]; }
#pragma unroll
    for (int r = 0; r < 16; ++r) { T1[r] = exp2f(T1[r] - mnew); rs += T1[r]; }
    // lrun stays lane-local (esc is uniform across the lane pair); merged in epilogue
    if (skip) {
      lrun += rs;
    } else {
      const float esc = exp2f(mrun - mnew);
      mrun = mnew;
      lrun = lrun * esc + rs;
#pragma unroll
      for (int r = 0; r < 16; ++r) { accT[0][r] *= esc; accT[1][r] *= esc; }
    }

    u32 P0[8], P1[8];
#pragma unroll
    for (int wd = 0; wd < 8; ++wd) {
      asm("v_cvt_pk_bf16_f32 %0, %1, %2" : "=v"(P0[wd]) : "v"(T0[2 * wd]), "v"(T0[2 * wd + 1]));
      asm("v_cvt_pk_bf16_f32 %0, %1, %2" : "=v"(P1[wd]) : "v"(T1[2 * wd]), "v"(T1[2 * wd + 1]));
    }
    bf16v8 pf[4];
    MKPF(pf[0], P0[0], P0[1], P0[2], P0[3]);
    MKPF(pf[1], P0[4], P0[5], P0[6], P0[7]);
    MKPF(pf[2], P1[0], P1[1], P1[2], P1[3]);
    MKPF(pf[3], P1[4], P1[5], P1[6], P1[7]);

#pragma unroll
    for (int dblk = 0; dblk < 2; ++dblk) {
      const int dd = dblk * 32 + l31;
      const int drow = (dd ^ (dd >> 3)) * 8;
#pragma unroll
      for (int ks = 0; ks < 4; ++ks) {
        const bf16v8 va = *(const bf16v8*)(sVt[cur] + (2 * ks + hi) * 512 + drow);
        accT[dblk] = __builtin_amdgcn_mfma_f32_32x32x16_bf16(va, pf[ks], accT[dblk], 0, 0, 0);
      }
    }

    if (t < 15) vt_write64(sVt[cur ^ 1], vreg, kr, s8);
    __syncthreads();
  }

  // ---- epilogue: merge lane-local lrun across halves, normalize, store ----
  lrun += __shfl_xor(lrun, 32);
  const float linv = 1.f / lrun;
  u16* orow = attn + obase + (size_t)(qrow0 + l31) * E_DIM;
#pragma unroll
  for (int dblk = 0; dblk < 2; ++dblk)
#pragma unroll
    for (int a4 = 0; a4 < 4; ++a4) {
      ushort4 st;
      st.x = f2b(accT[dblk][4 * a4 + 0] * linv);
      st.y = f2b(accT[dblk][4 * a4 + 1] * linv);
      st.z = f2b(accT[dblk][4 * a4 + 2] * linv);
      st.w = f2b(accT[dblk][4 * a4 + 3] * linv);
      *(ushort4*)(orow + dblk * 32 + a4 * 8 + hi * 4) = st;
    }
}

// ---------------- LayerNorm over bf16 inputs (1 block = 1 row of 1024), ddof=1 ----
// MODE 0: y = 2*(a+b), bf16 out (ln1 over Wo split-K partials)
// MODE 1: y = a+b+c,  f32 out  (ln2 over x1 + FFN2 partials)
template<int MODE>
__global__ __launch_bounds__(256) void ln_b16(
    const u16* __restrict__ a, const u16* __restrict__ b, const u16* __restrict__ c,
    const float* __restrict__ scale, const float* __restrict__ bias,
    float* __restrict__ outf, u16* __restrict__ outb) {
  const int row = blockIdx.x;
  const int tid = threadIdx.x;
  const size_t off = (size_t)row * 1024 + tid * 4;
  ushort4 av = *(const ushort4*)(a + off);
  ushort4 bv = *(const ushort4*)(b + off);
  float4 v;
  v.x = b2f(av.x) + b2f(bv.x);
  v.y = b2f(av.y) + b2f(bv.y);
  v.z = b2f(av.z) + b2f(bv.z);
  v.w = b2f(av.w) + b2f(bv.w);
  if (MODE == 0) {
    v.x *= 2.f; v.y *= 2.f; v.z *= 2.f; v.w *= 2.f;
  } else {
    ushort4 cv = *(const ushort4*)(c + off);
    v.x += b2f(cv.x); v.y += b2f(cv.y); v.z += b2f(cv.z); v.w += b2f(cv.w);
  }
  float s = v.x + v.y + v.z + v.w;
  float q = v.x * v.x + v.y * v.y + v.z * v.z + v.w * v.w;
#pragma unroll
  for (int o = 1; o < 64; o <<= 1) { s += __shfl_xor(s, o); q += __shfl_xor(q, o); }
  __shared__ float red[8];
  const int wave = tid >> 6, lane = tid & 63;
  if (lane == 0) { red[wave] = s; red[4 + wave] = q; }
  __syncthreads();
  s = red[0] + red[1] + red[2] + red[3];
  q = red[4] + red[5] + red[6] + red[7];
  const float mean = s * (1.f / 1024.f);
  const float var = (q - 1024.f * mean * mean) * (1.f / 1023.f);
  const float rstd = rsqrtf(var + 1e-5f);
  const int cc = tid * 4;
  float4 sc = *(const float4*)(scale + cc);
  float4 bi = *(const float4*)(bias + cc);
  float4 o;
  o.x = sc.x * (v.x - mean) * rstd + bi.x;
  o.y = sc.y * (v.y - mean) * rstd + bi.y;
  o.z = sc.z * (v.z - mean) * rstd + bi.z;
  o.w = sc.w * (v.w - mean) * rstd + bi.w;
  if (MODE == 0) {
    ushort4 ob;
    ob.x = f2b(o.x); ob.y = f2b(o.y); ob.z = f2b(o.z); ob.w = f2b(o.w);
    *(ushort4*)(outb + off) = ob;
  } else {
    *(float4*)(outf + off) = o;
  }
}

// ---------------- fp32 -> bf16 cast (4 elems/thread) ----------------
__global__ __launch_bounds__(256) void cast_bf16_k(const float* __restrict__ in,
                                                   u16* __restrict__ out, int n4) {
  const int i = blockIdx.x * blockDim.x + threadIdx.x;
  if (i >= n4) return;
  float4 v = *(const float4*)(in + (size_t)i * 4);
  ushort4 o;
  o.x = f2b(v.x); o.y = f2b(v.y); o.z = f2b(v.z); o.w = f2b(v.w);
  *(ushort4*)(out + (size_t)i * 4) = o;
}

// ---------------- 1024x1024 fp32 transpose + bf16 cast ----------------
__global__ __launch_bounds__(256) void transpose_cast_k(const float* __restrict__ in,
                                                        u16* __restrict__ out) {
  __shared__ float tile[32][33];
  const int tx = threadIdx.x & 31, ty = threadIdx.x >> 5;
  const int bx = blockIdx.x * 32, by = blockIdx.y * 32;
#pragma unroll
  for (int j = 0; j < 4; j++)
    tile[ty + j * 8][tx] = in[(size_t)(by + ty + j * 8) * 1024 + bx + tx];
  __syncthreads();
#pragma unroll
  for (int j = 0; j < 4; j++)
    out[(size_t)(bx + ty + j * 8) * 1024 + by + tx] = f2b(tile[tx][ty + j * 8]);
}

extern "C" void kernel_launch(void* const* d_in, const int* in_sizes, int n_in,
                              void* d_out, int out_size, void* d_ws, size_t ws_size,
                              hipStream_t stream) {
  const float* x    = (const float*)d_in[0];
  const float* in_w = (const float*)d_in[1];
  const float* out_w = (const float*)d_in[2];
  const float* ln1s = (const float*)d_in[3];
  const float* ln1b = (const float*)d_in[4];
  const float* ln2s = (const float*)d_in[5];
  const float* ln2b = (const float*)d_in[6];
  const float* w1   = (const float*)d_in[7];
  const float* b1   = (const float*)d_in[8];
  const float* w2   = (const float*)d_in[9];
  const float* b2   = (const float*)d_in[10];
  float* outp = (float*)d_out;

  char* ws = (char*)d_ws;
  // arena (peak 176,160,768 B):
  u16*   xb    = (u16*)(ws + 0);            // 16.8M; dead after QKV gemm
  u16*   qkv   = (u16*)(ws + 16777216);     // 50.3M; dead after attn
  u16*   attnb = (u16*)(ws + 0);            // 16.8M over dead xb; dead after Wo
  u16*   wo0   = (u16*)(ws + 67108864);     // 16.8M bf16 partial; dead after ln1
  u16*   wo1   = (u16*)(ws + 83886080);     // 16.8M bf16 partial; dead after ln1
  u16*   x1b   = (u16*)(ws + 100663296);    // 16.8M; read by FFN1 and ln2
  u16*   Hb    = (u16*)(ws + 0);            // 67.1M over dead xb/qkv/attnb
  u16*   ffn0b = (u16*)(ws + 67108864);     // 16.8M over dead wo0
  u16*   ffn1b = (u16*)(ws + 83886080);     // 16.8M over dead wo1
  u16*   wkt   = (u16*)(ws + 150994944);    // [3072][1024] concat k,q,v transposed
  u16*   wot   = wkt + 3145728;
  u16*   w1b   = wot + 1048576;
  u16*   w2b   = w1b + 4194304;
  (void)ws_size; (void)in_sizes; (void)n_in; (void)out_size;

  // casts / transposes
  cast_bf16_k<<<8192, 256, 0, stream>>>(x, xb, 2097152);
  cast_bf16_k<<<4096, 256, 0, stream>>>(w1, w1b, 1048576);
  cast_bf16_k<<<4096, 256, 0, stream>>>(w2, w2b, 1048576);
  dim3 tg(32, 32);
  transpose_cast_k<<<tg, 256, 0, stream>>>(in_w + 0,       wkt);            // k
  transpose_cast_k<<<tg, 256, 0, stream>>>(in_w + 1048576, wkt + 1048576); // q
  transpose_cast_k<<<tg, 256, 0, stream>>>(in_w + 2097152, wkt + 2097152); // v
  transpose_cast_k<<<tg, 256, 0, stream>>>(out_w,          wot);

  // fused QKV projection: [8192][3072], q block scaled by QK_SCALE
  gemm8<0><<<dim3(12, 32), 512, 0, stream>>>(xb, wkt, qkv, nullptr, nullptr, 3072, 1024, 12, 16);

  // attention: 512 blocks x 512 threads (256 q rows per block)
  attn_fa<<<512, 512, 0, stream>>>(qkv, attnb);

  // output projection, split-K=2 -> two bf16 partials
  gemm8<1><<<dim3(8, 32), 512, 0, stream>>>(attnb, wot, wo0, wo1, nullptr, 1024, 1024, 4, 8);

  // ln1: x1 = LN(2*(wo0+wo1)) -> bf16
  ln_b16<0><<<8192, 256, 0, stream>>>(wo0, wo1, nullptr, ln1s, ln1b, nullptr, x1b);

  // FFN1: bf16 + bias + relu
  gemm8<2><<<dim3(16, 32), 512, 0, stream>>>(x1b, w1b, Hb, nullptr, b1, 4096, 1024, 16, 16);

  // FFN2: split-K=2, bf16 partials (bias on partial 0)
  gemm8<3><<<dim3(8, 32), 512, 0, stream>>>(Hb, w2b, ffn0b, ffn1b, b2, 1024, 4096, 4, 32);

  // ln2: out = LN(x1 + ffn0 + ffn1) -> f32
  ln_b16<1><<<8192, 256, 0, stream>>>(x1b, ffn0b, ffn1b, ln2s, ln2b, outp, nullptr);
}